// Round 8
// baseline (243.656 us; speedup 1.0000x reference)
//
#include <hip/hip_runtime.h>
#include <hip/hip_bf16.h>
#include <math.h>

#define NN 65536          // nodes
#define NE 196608         // edges (without self loops)
#define ET (NE + NN)      // edges + self loops = 262144
#define NG 2048           // graphs
#define FIN 9
#define DD 128
#define H1 10
#define KK (H1 * DD)      // 1280
#define LRS 0.2f

typedef __attribute__((ext_vector_type(8))) short short8v;
typedef __attribute__((ext_vector_type(4))) float f32x4;

__device__ __forceinline__ float lrelu(float v) { return v >= 0.f ? v : LRS * v; }
__device__ __forceinline__ float eluf(float v)  { return v > 0.f ? v : expm1f(v); }

// float -> bf16 round-to-nearest-even (3 int ops, no libcall)
__device__ __forceinline__ unsigned short f2bf(float f) {
    unsigned int u = __float_as_uint(f);
    u += 0x7FFFu + ((u >> 16) & 1u);
    return (unsigned short)(u >> 16);
}
__device__ __forceinline__ float bf2f(unsigned short s) {
    return __uint_as_float((unsigned int)s << 16);
}

// ---- setup kernel: packW2 (blocks 0..639) | alpha1+prep (640..895) |
// ---- gptr (896..1151). All branches independent. --------------------------
__global__ __launch_bounds__(256) void setup_kernel(
        const float* __restrict__ W1, const float* __restrict__ W2,
        const float* __restrict__ a_src1, const float* __restrict__ a_dst1,
        const float* __restrict__ x, const int* __restrict__ batch,
        unsigned short* __restrict__ W2p,
        float* __restrict__ as1, float* __restrict__ ad1,
        int* __restrict__ deg, int* __restrict__ gptr) {
    __shared__ float ws_s[FIN * H1], wd_s[FIN * H1];
    const int b = blockIdx.x;
    const int t = threadIdx.x;
    if (b < 640) {
        // pack W2 (1280x128 fp32) -> bf16 B-fragment layout
        int idx = b * 256 + t;
        int r  = idx & 7;
        int l  = (idx >> 3) & 63;
        int nt = (idx >> 9) & 7;
        int kt = idx >> 12;
        int k = kt * 32 + ((l >> 4) << 3) + r;
        int n = nt * 16 + (l & 15);
        W2p[idx] = f2bf(W2[(size_t)k * DD + n]);
    } else if (b < 896) {
        // per-block prep: fold W1 into per-head 9-dim logit vectors
        if (t < FIN * H1) {
            int f = t / H1, h = t - f * H1;
            float s = 0.f, d = 0.f;
            for (int c = 0; c < DD; ++c) {
                float w = W1[f * KK + h * DD + c];
                s = fmaf(w, a_src1[h * DD + c], s);
                d = fmaf(w, a_dst1[h * DD + c], d);
            }
            ws_s[t] = s;
            wd_s[t] = d;
        }
        __syncthreads();
        int n = (b - 640) * 256 + t;
        float xv[FIN];
#pragma unroll
        for (int f = 0; f < FIN; ++f) xv[f] = x[(size_t)n * FIN + f];
#pragma unroll
        for (int h = 0; h < H1; ++h) {
            float s = 0.f, d = 0.f;
#pragma unroll
            for (int f = 0; f < FIN; ++f) {
                s = fmaf(xv[f], ws_s[f * H1 + h], s);
                d = fmaf(xv[f], wd_s[f * H1 + h], d);
            }
            as1[n * H1 + h] = s;
            ad1[n * H1 + h] = d;
        }
        deg[n] = 0;
    } else {
        // per-graph node ranges from the sorted batch vector
        int n = (b - 896) * 256 + t;
        int bn = batch[n];
        int bp = (n == 0) ? -1 : batch[n - 1];
        for (int g = bp + 1; g <= bn; ++g) gptr[g] = n;
        if (n == NN - 1) {
            for (int g = bn + 1; g <= NG; ++g) gptr[g] = NN;
        }
    }
}

// ---- CSR build: count / scan / scatter --------------------------------------
__global__ void count_kernel(const int* __restrict__ ei, int* __restrict__ deg) {
    int e = blockIdx.x * 256 + threadIdx.x;
    if (e >= ET) return;
    int d = (e < NE) ? ei[NE + e] : e - NE;
    atomicAdd(&deg[d], 1);
}

__global__ __launch_bounds__(1024) void scan_kernel(const int* __restrict__ deg,
                                                    int* __restrict__ rowptr,
                                                    int* __restrict__ cursor) {
    __shared__ int part[1024];
    int t = threadIdx.x;
    int sum = 0;
    for (int i = 0; i < 64; ++i) sum += deg[t * 64 + i];
    part[t] = sum;
    __syncthreads();
    for (int off = 1; off < 1024; off <<= 1) {
        int v = (t >= off) ? part[t - off] : 0;
        __syncthreads();
        part[t] += v;
        __syncthreads();
    }
    int run = (t == 0) ? 0 : part[t - 1];
    for (int i = 0; i < 64; ++i) {
        int idx = t * 64 + i;
        rowptr[idx] = run;
        cursor[idx] = run;
        run += deg[idx];
    }
    if (t == 1023) rowptr[NN] = run;
}

__global__ void scatter_kernel(const int* __restrict__ ei, int* __restrict__ cursor,
                               int* __restrict__ elist) {
    int e = blockIdx.x * 256 + threadIdx.x;
    if (e >= ET) return;
    int s, d;
    if (e < NE) { s = ei[e]; d = ei[NE + e]; } else { s = d = e - NE; }
    int pos = atomicAdd(&cursor[d], 1);
    elist[pos] = s;
}

// ---- layer-1 aggregation: gather-side, ONLINE softmax, TRANSPOSED output ----
// xaggT[(h*FIN+f)*NN + d] so the GEMM build reads lane-coalesced columns.
__global__ void agg1_kernel(const int* __restrict__ rowptr, const int* __restrict__ elist,
                            const float* __restrict__ x,
                            const float* __restrict__ as1, const float* __restrict__ ad1,
                            float* __restrict__ xaggT) {
    int idx = blockIdx.x * 256 + threadIdx.x;     // NN*H1
    if (idx >= NN * H1) return;
    int d = idx / H1, h = idx - d * H1;
    int beg = rowptr[d], end = rowptr[d + 1];
    float adh = ad1[d * H1 + h];
    float m = -INFINITY, den = 0.f;
    float xa[FIN] = {};
    for (int j = beg; j < end; ++j) {
        int s = elist[j];
        float v = lrelu(as1[s * H1 + h] + adh);
        if (v > m) {
            float sc = __expf(m - v);
            den *= sc;
#pragma unroll
            for (int f = 0; f < FIN; ++f) xa[f] *= sc;
            m = v;
        }
        float ex = __expf(v - m);
        den += ex;
        const float* xs = &x[(size_t)s * FIN];
#pragma unroll
        for (int f = 0; f < FIN; ++f) xa[f] = fmaf(ex, xs[f], xa[f]);
    }
    float inv = 1.f / (den + 1e-16f);
#pragma unroll
    for (int f = 0; f < FIN; ++f)
        xaggT[((size_t)(h * FIN + f)) * NN + d] = xa[f] * inv;
}

// ---- fused h2 = elu(xaggT@W1 + b1) @ W2 via MFMA + alpha2 epilogue ----------
// v4: no xagg LDS stage (coalesced L2-hot reads from xaggT), single Xs buffer
// (8.7 KB LDS), launch_bounds(256,8) targets <=64 VGPR -> 8 blocks/CU so TLP
// hides build latency. h2 written as bf16 only (halves agg2 gather bytes).
__global__ __launch_bounds__(256, 8) void h2_gemm(const float* __restrict__ xaggT,
                                                  const float* __restrict__ W1,
                                                  const float* __restrict__ b1,
                                                  const unsigned short* __restrict__ W2p,
                                                  const float* __restrict__ a_src2,
                                                  const float* __restrict__ a_dst2,
                                                  unsigned short* __restrict__ h2b,
                                                  float* __restrict__ as2,
                                                  float* __restrict__ ad2) {
    __shared__ unsigned short Xs[64 * 64];        // 8 KB, XOR-swizzled 16B granules
    __shared__ float as_s[64], ad_s[64];
    const int t = threadIdx.x;
    const int n0 = blockIdx.x * 64;
    const int row = t & 63;
    const int wvu = __builtin_amdgcn_readfirstlane(t >> 6);
    const int lane = t & 63;
    const int rlo = lane & 15, khi = lane >> 4;
    if (t < 64) { as_s[t] = 0.f; ad_s[t] = 0.f; }

    f32x4 acc[4][2];
#pragma unroll
    for (int mt = 0; mt < 4; ++mt)
#pragma unroll
        for (int ntl = 0; ntl < 2; ++ntl)
#pragma unroll
            for (int q = 0; q < 4; ++q) acc[mt][ntl][q] = 0.f;

    for (int s = 0; s < 20; ++s) {
        const int h = s >> 1;
        const int k0 = s << 6;
        // build this thread's row of the x1 tile: 16 cols (wave-uniform W1 cols)
        float xa[FIN];
#pragma unroll
        for (int f = 0; f < FIN; ++f)
            xa[f] = xaggT[((size_t)(h * FIN + f)) * NN + n0 + row];
        const float* w1s = W1 + (size_t)(k0 + wvu * 16);
        const float* b1s = b1 + (k0 + wvu * 16);
        float z[16];
#pragma unroll
        for (int c = 0; c < 16; ++c) z[c] = b1s[c];
#pragma unroll
        for (int f = 0; f < FIN; ++f)
#pragma unroll
            for (int c = 0; c < 16; ++c)
                z[c] = fmaf(xa[f], w1s[(size_t)f * KK + c], z[c]);
        unsigned int pk[8];
#pragma unroll
        for (int p = 0; p < 8; ++p) {
            float lo = z[2 * p], hi = z[2 * p + 1];
            lo = lo > 0.f ? lo : __expf(lo) - 1.f;
            hi = hi > 0.f ? hi : __expf(hi) - 1.f;
            pk[p] = (unsigned int)f2bf(lo) | ((unsigned int)f2bf(hi) << 16);
        }
        __syncthreads();                  // prev-iter MFMA reads of Xs done
#pragma unroll
        for (int j = 0; j < 2; ++j) {
            int g = wvu * 2 + j;
            uint4 v = make_uint4(pk[j * 4 + 0], pk[j * 4 + 1], pk[j * 4 + 2], pk[j * 4 + 3]);
            *(uint4*)&Xs[row * 64 + ((g ^ (row & 7)) << 3)] = v;
        }
        __syncthreads();
#pragma unroll
        for (int ks = 0; ks < 2; ++ks) {
            const int ktabs = s * 2 + ks;
            short8v bfr[2];
#pragma unroll
            for (int ntl = 0; ntl < 2; ++ntl) {
                const int nt = wvu * 2 + ntl;
                bfr[ntl] = *(const short8v*)&W2p[(((size_t)ktabs * 8 + nt) * 64 + lane) * 8];
            }
#pragma unroll
            for (int mt = 0; mt < 4; ++mt) {
                const int row2 = mt * 16 + rlo;
                const int gk = ks * 4 + khi;
                short8v af = *(const short8v*)&Xs[row2 * 64 + ((gk ^ (row2 & 7)) << 3)];
                acc[mt][0] = __builtin_amdgcn_mfma_f32_16x16x32_bf16(af, bfr[0], acc[mt][0], 0, 0, 0);
                acc[mt][1] = __builtin_amdgcn_mfma_f32_16x16x32_bf16(af, bfr[1], acc[mt][1], 0, 0, 0);
            }
        }
    }

    // C write (bf16): col = lane&15, row = (lane>>4)*4 + reg
#pragma unroll
    for (int mt = 0; mt < 4; ++mt)
#pragma unroll
        for (int ntl = 0; ntl < 2; ++ntl)
#pragma unroll
            for (int q = 0; q < 4; ++q) {
                int r2 = n0 + mt * 16 + khi * 4 + q;
                int c2 = wvu * 32 + ntl * 16 + rlo;
                h2b[(size_t)r2 * DD + c2] = f2bf(acc[mt][ntl][q]);
            }

    // fused alpha2 from fp32 accumulators
    float sp[16], dp[16];
#pragma unroll
    for (int mt = 0; mt < 4; ++mt)
#pragma unroll
        for (int q = 0; q < 4; ++q) {
            float a = 0.f, b = 0.f;
#pragma unroll
            for (int ntl = 0; ntl < 2; ++ntl) {
                int col = wvu * 32 + ntl * 16 + rlo;
                float v = acc[mt][ntl][q];
                a = fmaf(v, a_src2[col], a);
                b = fmaf(v, a_dst2[col], b);
            }
            sp[mt * 4 + q] = a;
            dp[mt * 4 + q] = b;
        }
#pragma unroll
    for (int off = 1; off < 16; off <<= 1) {
#pragma unroll
        for (int i = 0; i < 16; ++i) {
            sp[i] += __shfl_xor(sp[i], off);
            dp[i] += __shfl_xor(dp[i], off);
        }
    }
    if (rlo == 0) {
#pragma unroll
        for (int mt = 0; mt < 4; ++mt)
#pragma unroll
            for (int q = 0; q < 4; ++q) {
                atomicAdd(&as_s[mt * 16 + khi * 4 + q], sp[mt * 4 + q]);
                atomicAdd(&ad_s[mt * 16 + khi * 4 + q], dp[mt * 4 + q]);
            }
    }
    __syncthreads();
    if (t < 64) {
        as2[n0 + t] = as_s[t];
        ad2[n0 + t] = ad_s[t];
    }
}

// ---- layer-2 aggregation (online softmax, bf16 h2) -> x2 --------------------
__global__ void agg2_kernel(const int* __restrict__ rowptr, const int* __restrict__ elist,
                            const unsigned short* __restrict__ h2b,
                            const float* __restrict__ as2, const float* __restrict__ ad2,
                            const float* __restrict__ b2, float* __restrict__ x2) {
    int gid = blockIdx.x * 256 + threadIdx.x;
    int n = gid >> 5, lane = gid & 31;
    if (n >= NN) return;
    int beg = rowptr[n], end = rowptr[n + 1];
    float adn = ad2[n];
    float m = -INFINITY, den = 0.f;
    float4 acc = make_float4(0.f, 0.f, 0.f, 0.f);
    for (int j = beg; j < end; ++j) {
        int s = elist[j];
        float v = lrelu(as2[s] + adn);
        if (v > m) {
            float sc = __expf(m - v);
            den *= sc;
            acc.x *= sc; acc.y *= sc; acc.z *= sc; acc.w *= sc;
            m = v;
        }
        float ex = __expf(v - m);
        den += ex;
        ushort4 hv = *(const ushort4*)&h2b[(size_t)s * DD + lane * 4];
        acc.x = fmaf(ex, bf2f(hv.x), acc.x);
        acc.y = fmaf(ex, bf2f(hv.y), acc.y);
        acc.z = fmaf(ex, bf2f(hv.z), acc.z);
        acc.w = fmaf(ex, bf2f(hv.w), acc.w);
    }
    float inv = 1.f / (den + 1e-16f);
    float4 bv = *(const float4*)&b2[lane * 4];
    float4 r;
    r.x = eluf(acc.x * inv + bv.x);
    r.y = eluf(acc.y * inv + bv.y);
    r.z = eluf(acc.z * inv + bv.z);
    r.w = eluf(acc.w * inv + bv.w);
    *(float4*)&x2[(size_t)n * DD + lane * 4] = r;
}

// ---- fused pooling + FC: block g pools its node range, then out row g -------
__global__ __launch_bounds__(128) void pool_final_kernel(const int* __restrict__ gptr,
                                                         const float* __restrict__ x2,
                                                         const float* __restrict__ Wfc,
                                                         const float* __restrict__ bfc,
                                                         float* __restrict__ out) {
    __shared__ float pl[DD];
    int g = blockIdx.x;
    int c = threadIdx.x;          // 128 channels
    int beg = gptr[g], end = gptr[g + 1];
    float v = -INFINITY;
    for (int n = beg; n < end; ++n)
        v = fmaxf(v, x2[(size_t)n * DD + c]);
    if (beg == end) v = 0.f;      // empty graph -> 0 (isfinite guard)
    pl[c] = v;
    __syncthreads();
    float acc = bfc[c];
#pragma unroll 8
    for (int k = 0; k < DD; ++k)
        acc = fmaf(pl[k], Wfc[k * DD + c], acc);
    out[(size_t)g * DD + c] = acc > 0.f ? acc : 0.f;
}

extern "C" void kernel_launch(void* const* d_in, const int* in_sizes, int n_in,
                              void* d_out, int out_size, void* d_ws, size_t ws_size,
                              hipStream_t stream) {
    const float* x      = (const float*)d_in[0];
    const int*   ei     = (const int*)d_in[1];
    const int*   batch  = (const int*)d_in[3];
    const float* W1     = (const float*)d_in[4];
    const float* a_src1 = (const float*)d_in[5];
    const float* a_dst1 = (const float*)d_in[6];
    const float* b1     = (const float*)d_in[7];
    const float* W2     = (const float*)d_in[8];
    const float* a_src2 = (const float*)d_in[9];
    const float* a_dst2 = (const float*)d_in[10];
    const float* b2     = (const float*)d_in[11];
    const float* Wfc    = (const float*)d_in[12];
    const float* bfc    = (const float*)d_in[13];
    float* out = (float*)d_out;

    // workspace layout — ~86 MB total
    float* wsf    = (float*)d_ws;
    float* as1    = wsf;                                   // NN*H1
    float* ad1    = as1 + (size_t)NN * H1;                 // NN*H1
    float* xaggT  = ad1 + (size_t)NN * H1;                 // NN*H1*FIN (transposed)
    float* as2    = xaggT + (size_t)NN * H1 * FIN;         // NN
    float* ad2    = as2 + NN;                              // NN
    float* x2     = ad2 + NN;                              // NN*DD
    int*   deg    = (int*)(x2 + (size_t)NN * DD);          // NN
    int*   rowptr = deg + NN;                              // NN+1
    int*   cursor = rowptr + NN + 1;                       // NN
    int*   elist  = cursor + NN;                           // ET
    int*   gptr   = elist + ET;                            // NG+1
    size_t off = (size_t)((char*)(gptr + NG + 1) - (char*)d_ws);
    off = (off + 15) & ~(size_t)15;
    unsigned short* W2p = (unsigned short*)((char*)d_ws + off);      // KK*DD bf16
    unsigned short* h2b = W2p + (size_t)KK * DD;                     // NN*DD bf16

    setup_kernel     <<<1152, 256, 0, stream>>>(W1, W2, a_src1, a_dst1, x, batch,
                                                W2p, as1, ad1, deg, gptr);
    count_kernel     <<<(ET + 255) / 256, 256, 0, stream>>>(ei, deg);
    scan_kernel      <<<1, 1024, 0, stream>>>(deg, rowptr, cursor);
    scatter_kernel   <<<(ET + 255) / 256, 256, 0, stream>>>(ei, cursor, elist);
    agg1_kernel      <<<(NN * H1 + 255) / 256, 256, 0, stream>>>(rowptr, elist, x, as1, ad1, xaggT);
    h2_gemm          <<<NN / 64, 256, 0, stream>>>(xaggT, W1, b1, W2p, a_src2, a_dst2,
                                                   h2b, as2, ad2);
    agg2_kernel      <<<(NN * 32) / 256, 256, 0, stream>>>(rowptr, elist, h2b, as2, ad2, b2, x2);
    pool_final_kernel<<<NG, 128, 0, stream>>>(gptr, x2, Wfc, bfc, out);
}

// Round 9
// 216.383 us; speedup vs baseline: 1.1260x; 1.1260x over previous
//
#include <hip/hip_runtime.h>
#include <hip/hip_bf16.h>
#include <math.h>

#define NN 65536          // nodes
#define NE 196608         // edges (without self loops)
#define ET (NE + NN)      // edges + self loops = 262144
#define NG 2048           // graphs
#define FIN 9
#define DD 128
#define H1 10
#define KK (H1 * DD)      // 1280
#define LRS 0.2f

typedef __attribute__((ext_vector_type(8))) short short8v;
typedef __attribute__((ext_vector_type(4))) float f32x4;

__device__ __forceinline__ float lrelu(float v) { return v >= 0.f ? v : LRS * v; }
__device__ __forceinline__ float eluf(float v)  { return v > 0.f ? v : expm1f(v); }

// float -> bf16 round-to-nearest-even (3 int ops, no libcall)
__device__ __forceinline__ unsigned short f2bf(float f) {
    unsigned int u = __float_as_uint(f);
    u += 0x7FFFu + ((u >> 16) & 1u);
    return (unsigned short)(u >> 16);
}

// ---- setup kernel: packW2 (blocks 0..639) | alpha1+prep (640..895) |
// ---- gptr (896..1151). All branches independent. --------------------------
__global__ __launch_bounds__(256) void setup_kernel(
        const float* __restrict__ W1, const float* __restrict__ W2,
        const float* __restrict__ a_src1, const float* __restrict__ a_dst1,
        const float* __restrict__ x, const int* __restrict__ batch,
        unsigned short* __restrict__ W2p,
        float* __restrict__ as1, float* __restrict__ ad1,
        int* __restrict__ deg, int* __restrict__ gptr) {
    __shared__ float ws_s[FIN * H1], wd_s[FIN * H1];
    const int b = blockIdx.x;
    const int t = threadIdx.x;
    if (b < 640) {
        int idx = b * 256 + t;
        int r  = idx & 7;
        int l  = (idx >> 3) & 63;
        int nt = (idx >> 9) & 7;
        int kt = idx >> 12;
        int k = kt * 32 + ((l >> 4) << 3) + r;
        int n = nt * 16 + (l & 15);
        W2p[idx] = f2bf(W2[(size_t)k * DD + n]);
    } else if (b < 896) {
        if (t < FIN * H1) {
            int f = t / H1, h = t - f * H1;
            float s = 0.f, d = 0.f;
            for (int c = 0; c < DD; ++c) {
                float w = W1[f * KK + h * DD + c];
                s = fmaf(w, a_src1[h * DD + c], s);
                d = fmaf(w, a_dst1[h * DD + c], d);
            }
            ws_s[t] = s;
            wd_s[t] = d;
        }
        __syncthreads();
        int n = (b - 640) * 256 + t;
        float xv[FIN];
#pragma unroll
        for (int f = 0; f < FIN; ++f) xv[f] = x[(size_t)n * FIN + f];
#pragma unroll
        for (int h = 0; h < H1; ++h) {
            float s = 0.f, d = 0.f;
#pragma unroll
            for (int f = 0; f < FIN; ++f) {
                s = fmaf(xv[f], ws_s[f * H1 + h], s);
                d = fmaf(xv[f], wd_s[f * H1 + h], d);
            }
            as1[n * H1 + h] = s;
            ad1[n * H1 + h] = d;
        }
        deg[n] = 0;
    } else {
        int n = (b - 896) * 256 + t;
        int bn = batch[n];
        int bp = (n == 0) ? -1 : batch[n - 1];
        for (int g = bp + 1; g <= bn; ++g) gptr[g] = n;
        if (n == NN - 1) {
            for (int g = bn + 1; g <= NG; ++g) gptr[g] = NN;
        }
    }
}

// ---- CSR build: count / scan / scatter --------------------------------------
__global__ void count_kernel(const int* __restrict__ ei, int* __restrict__ deg) {
    int e = blockIdx.x * 256 + threadIdx.x;
    if (e >= ET) return;
    int d = (e < NE) ? ei[NE + e] : e - NE;
    atomicAdd(&deg[d], 1);
}

__global__ __launch_bounds__(1024) void scan_kernel(const int* __restrict__ deg,
                                                    int* __restrict__ rowptr,
                                                    int* __restrict__ cursor) {
    __shared__ int part[1024];
    int t = threadIdx.x;
    int sum = 0;
    for (int i = 0; i < 64; ++i) sum += deg[t * 64 + i];
    part[t] = sum;
    __syncthreads();
    for (int off = 1; off < 1024; off <<= 1) {
        int v = (t >= off) ? part[t - off] : 0;
        __syncthreads();
        part[t] += v;
        __syncthreads();
    }
    int run = (t == 0) ? 0 : part[t - 1];
    for (int i = 0; i < 64; ++i) {
        int idx = t * 64 + i;
        rowptr[idx] = run;
        cursor[idx] = run;
        run += deg[idx];
    }
    if (t == 1023) rowptr[NN] = run;
}

__global__ void scatter_kernel(const int* __restrict__ ei, int* __restrict__ cursor,
                               int* __restrict__ elist) {
    int e = blockIdx.x * 256 + threadIdx.x;
    if (e >= ET) return;
    int s, d;
    if (e < NE) { s = ei[e]; d = ei[NE + e]; } else { s = d = e - NE; }
    int pos = atomicAdd(&cursor[d], 1);
    elist[pos] = s;
}

// ---- layer-1 aggregation: gather-side, ONLINE softmax, row-major output -----
__global__ void agg1_kernel(const int* __restrict__ rowptr, const int* __restrict__ elist,
                            const float* __restrict__ x,
                            const float* __restrict__ as1, const float* __restrict__ ad1,
                            float* __restrict__ xaggn) {
    int idx = blockIdx.x * 256 + threadIdx.x;     // NN*H1
    if (idx >= NN * H1) return;
    int d = idx / H1, h = idx - d * H1;
    int beg = rowptr[d], end = rowptr[d + 1];
    float adh = ad1[d * H1 + h];
    float m = -INFINITY, den = 0.f;
    float xa[FIN] = {};
    for (int j = beg; j < end; ++j) {
        int s = elist[j];
        float v = lrelu(as1[s * H1 + h] + adh);
        if (v > m) {
            float sc = __expf(m - v);
            den *= sc;
#pragma unroll
            for (int f = 0; f < FIN; ++f) xa[f] *= sc;
            m = v;
        }
        float ex = __expf(v - m);
        den += ex;
        const float* xs = &x[(size_t)s * FIN];
#pragma unroll
        for (int f = 0; f < FIN; ++f) xa[f] = fmaf(ex, xs[f], xa[f]);
    }
    float inv = 1.f / (den + 1e-16f);
    float* o = &xaggn[(size_t)idx * FIN];
#pragma unroll
    for (int f = 0; f < FIN; ++f) o[f] = xa[f] * inv;
}

// ---- fused h2 = elu(xaggn@W1 + b1) @ W2 via MFMA + alpha2 epilogue ----------
// v5: 8 waves (512 thr) per 64x128 block -> 32 waves/CU (4 blocks x 8).
// Each wave builds 64 rows x 8 cols (wave-uniform W1 -> scalar loads) and owns
// one 16-col N-tile for MFMA. Single Xs buffer; h2 fp32 coalesced.
__global__ __launch_bounds__(512, 8) void h2_gemm(const float* __restrict__ xaggn,
                                                  const float* __restrict__ W1,
                                                  const float* __restrict__ b1,
                                                  const unsigned short* __restrict__ W2p,
                                                  const float* __restrict__ a_src2,
                                                  const float* __restrict__ a_dst2,
                                                  float* __restrict__ h2,
                                                  float* __restrict__ as2,
                                                  float* __restrict__ ad2) {
    __shared__ float xagg_s[64 * 91];             // 23.3 KB (91: odd stride, conflict-free)
    __shared__ unsigned short Xs[64 * 64];        // 8 KB, XOR-swizzled 16B granules
    __shared__ float as_s[64], ad_s[64];
    const int t = threadIdx.x;
    const int n0 = blockIdx.x * 64;

    for (int idx = t; idx < 64 * 90; idx += 512) {
        int row = idx / 90, c = idx - row * 90;
        xagg_s[row * 91 + c] = xaggn[(size_t)n0 * 90 + idx];
    }
    if (t < 64) { as_s[t] = 0.f; ad_s[t] = 0.f; }

    const int lane = t & 63;
    const int wvu = __builtin_amdgcn_readfirstlane(t >> 6);   // 0..7
    const int row = lane;                                     // build row
    const int rlo = lane & 15, khi = lane >> 4;

    f32x4 acc[4];
#pragma unroll
    for (int mt = 0; mt < 4; ++mt)
#pragma unroll
        for (int q = 0; q < 4; ++q) acc[mt][q] = 0.f;

    __syncthreads();                     // xagg_s staged

    for (int s = 0; s < 20; ++s) {
        const int h = s >> 1;
        const int k0 = s << 6;
        // build: this wave's 8 cols (wave-uniform) for its 64 rows
        float xa[FIN];
#pragma unroll
        for (int f = 0; f < FIN; ++f) xa[f] = xagg_s[row * 91 + h * FIN + f];
        const float* w1s = W1 + (size_t)(k0 + wvu * 8);
        const float* b1s = b1 + (k0 + wvu * 8);
        float z[8];
#pragma unroll
        for (int c = 0; c < 8; ++c) z[c] = b1s[c];
#pragma unroll
        for (int f = 0; f < FIN; ++f)
#pragma unroll
            for (int c = 0; c < 8; ++c)
                z[c] = fmaf(xa[f], w1s[(size_t)f * KK + c], z[c]);
        unsigned int pk[4];
#pragma unroll
        for (int p = 0; p < 4; ++p) {
            float lo = z[2 * p], hi = z[2 * p + 1];
            lo = lo > 0.f ? lo : __expf(lo) - 1.f;
            hi = hi > 0.f ? hi : __expf(hi) - 1.f;
            pk[p] = (unsigned int)f2bf(lo) | ((unsigned int)f2bf(hi) << 16);
        }
        __syncthreads();                  // prev-iter MFMA reads of Xs done
        {
            uint4 v = make_uint4(pk[0], pk[1], pk[2], pk[3]);
            *(uint4*)&Xs[row * 64 + ((wvu ^ (row & 7)) << 3)] = v;
        }
        __syncthreads();
#pragma unroll
        for (int ks = 0; ks < 2; ++ks) {
            const int ktabs = s * 2 + ks;
            short8v bfr = *(const short8v*)&W2p[(((size_t)ktabs * 8 + wvu) * 64 + lane) * 8];
#pragma unroll
            for (int mt = 0; mt < 4; ++mt) {
                const int row2 = mt * 16 + rlo;
                const int gk = ks * 4 + khi;
                short8v af = *(const short8v*)&Xs[row2 * 64 + ((gk ^ (row2 & 7)) << 3)];
                acc[mt] = __builtin_amdgcn_mfma_f32_16x16x32_bf16(af, bfr, acc[mt], 0, 0, 0);
            }
        }
    }

    // C write (fp32, coalesced): col = wvu*16 + (lane&15), row = (lane>>4)*4+q
#pragma unroll
    for (int mt = 0; mt < 4; ++mt)
#pragma unroll
        for (int q = 0; q < 4; ++q) {
            int r2 = n0 + mt * 16 + khi * 4 + q;
            int c2 = wvu * 16 + rlo;
            h2[(size_t)r2 * DD + c2] = acc[mt][q];
        }

    // fused alpha2 from fp32 accumulators
    const float sa = a_src2[wvu * 16 + rlo];
    const float da = a_dst2[wvu * 16 + rlo];
    float sp[16], dp[16];
#pragma unroll
    for (int mt = 0; mt < 4; ++mt)
#pragma unroll
        for (int q = 0; q < 4; ++q) {
            sp[mt * 4 + q] = acc[mt][q] * sa;
            dp[mt * 4 + q] = acc[mt][q] * da;
        }
#pragma unroll
    for (int off = 1; off < 16; off <<= 1) {
#pragma unroll
        for (int i = 0; i < 16; ++i) {
            sp[i] += __shfl_xor(sp[i], off);
            dp[i] += __shfl_xor(dp[i], off);
        }
    }
    if (rlo == 0) {
#pragma unroll
        for (int mt = 0; mt < 4; ++mt)
#pragma unroll
            for (int q = 0; q < 4; ++q) {
                atomicAdd(&as_s[mt * 16 + khi * 4 + q], sp[mt * 4 + q]);
                atomicAdd(&ad_s[mt * 16 + khi * 4 + q], dp[mt * 4 + q]);
            }
    }
    __syncthreads();
    if (t < 64) {
        as2[n0 + t] = as_s[t];
        ad2[n0 + t] = ad_s[t];
    }
}

// ---- layer-2 aggregation (online softmax, fp32 h2) -> x2 --------------------
__global__ void agg2_kernel(const int* __restrict__ rowptr, const int* __restrict__ elist,
                            const float* __restrict__ h2,
                            const float* __restrict__ as2, const float* __restrict__ ad2,
                            const float* __restrict__ b2, float* __restrict__ x2) {
    int gid = blockIdx.x * 256 + threadIdx.x;
    int n = gid >> 5, lane = gid & 31;
    if (n >= NN) return;
    int beg = rowptr[n], end = rowptr[n + 1];
    float adn = ad2[n];
    float m = -INFINITY, den = 0.f;
    float4 acc = make_float4(0.f, 0.f, 0.f, 0.f);
    for (int j = beg; j < end; ++j) {
        int s = elist[j];
        float v = lrelu(as2[s] + adn);
        if (v > m) {
            float sc = __expf(m - v);
            den *= sc;
            acc.x *= sc; acc.y *= sc; acc.z *= sc; acc.w *= sc;
            m = v;
        }
        float ex = __expf(v - m);
        den += ex;
        float4 hv = *(const float4*)&h2[(size_t)s * DD + lane * 4];
        acc.x = fmaf(ex, hv.x, acc.x);
        acc.y = fmaf(ex, hv.y, acc.y);
        acc.z = fmaf(ex, hv.z, acc.z);
        acc.w = fmaf(ex, hv.w, acc.w);
    }
    float inv = 1.f / (den + 1e-16f);
    float4 bv = *(const float4*)&b2[lane * 4];
    float4 r;
    r.x = eluf(acc.x * inv + bv.x);
    r.y = eluf(acc.y * inv + bv.y);
    r.z = eluf(acc.z * inv + bv.z);
    r.w = eluf(acc.w * inv + bv.w);
    *(float4*)&x2[(size_t)n * DD + lane * 4] = r;
}

// ---- fused pooling + FC: block g pools its node range, then out row g -------
__global__ __launch_bounds__(128) void pool_final_kernel(const int* __restrict__ gptr,
                                                         const float* __restrict__ x2,
                                                         const float* __restrict__ Wfc,
                                                         const float* __restrict__ bfc,
                                                         float* __restrict__ out) {
    __shared__ float pl[DD];
    int g = blockIdx.x;
    int c = threadIdx.x;          // 128 channels
    int beg = gptr[g], end = gptr[g + 1];
    float v = -INFINITY;
    for (int n = beg; n < end; ++n)
        v = fmaxf(v, x2[(size_t)n * DD + c]);
    if (beg == end) v = 0.f;      // empty graph -> 0 (isfinite guard)
    pl[c] = v;
    __syncthreads();
    float acc = bfc[c];
#pragma unroll 8
    for (int k = 0; k < DD; ++k)
        acc = fmaf(pl[k], Wfc[k * DD + c], acc);
    out[(size_t)g * DD + c] = acc > 0.f ? acc : 0.f;
}

extern "C" void kernel_launch(void* const* d_in, const int* in_sizes, int n_in,
                              void* d_out, int out_size, void* d_ws, size_t ws_size,
                              hipStream_t stream) {
    const float* x      = (const float*)d_in[0];
    const int*   ei     = (const int*)d_in[1];
    const int*   batch  = (const int*)d_in[3];
    const float* W1     = (const float*)d_in[4];
    const float* a_src1 = (const float*)d_in[5];
    const float* a_dst1 = (const float*)d_in[6];
    const float* b1     = (const float*)d_in[7];
    const float* W2     = (const float*)d_in[8];
    const float* a_src2 = (const float*)d_in[9];
    const float* a_dst2 = (const float*)d_in[10];
    const float* b2     = (const float*)d_in[11];
    const float* Wfc    = (const float*)d_in[12];
    const float* bfc    = (const float*)d_in[13];
    float* out = (float*)d_out;

    // workspace layout — ~100 MB total
    float* wsf    = (float*)d_ws;
    float* as1    = wsf;                                   // NN*H1
    float* ad1    = as1 + (size_t)NN * H1;                 // NN*H1
    float* xaggn  = ad1 + (size_t)NN * H1;                 // NN*H1*FIN
    float* h2     = xaggn + (size_t)NN * H1 * FIN;         // NN*DD
    float* as2    = h2 + (size_t)NN * DD;                  // NN
    float* ad2    = as2 + NN;                              // NN
    float* x2     = ad2 + NN;                              // NN*DD
    int*   deg    = (int*)(x2 + (size_t)NN * DD);          // NN
    int*   rowptr = deg + NN;                              // NN+1
    int*   cursor = rowptr + NN + 1;                       // NN
    int*   elist  = cursor + NN;                           // ET
    int*   gptr   = elist + ET;                            // NG+1
    size_t off = (size_t)((char*)(gptr + NG + 1) - (char*)d_ws);
    off = (off + 15) & ~(size_t)15;
    unsigned short* W2p = (unsigned short*)((char*)d_ws + off);      // KK*DD bf16

    setup_kernel     <<<1152, 256, 0, stream>>>(W1, W2, a_src1, a_dst1, x, batch,
                                                W2p, as1, ad1, deg, gptr);
    count_kernel     <<<(ET + 255) / 256, 256, 0, stream>>>(ei, deg);
    scan_kernel      <<<1, 1024, 0, stream>>>(deg, rowptr, cursor);
    scatter_kernel   <<<(ET + 255) / 256, 256, 0, stream>>>(ei, cursor, elist);
    agg1_kernel      <<<(NN * H1 + 255) / 256, 256, 0, stream>>>(rowptr, elist, x, as1, ad1, xaggn);
    h2_gemm          <<<NN / 64, 512, 0, stream>>>(xaggn, W1, b1, W2p, a_src2, a_dst2,
                                                   h2, as2, ad2);
    agg2_kernel      <<<(NN * 32) / 256, 256, 0, stream>>>(rowptr, elist, h2, as2, ad2, b2, x2);
    pool_final_kernel<<<NG, 128, 0, stream>>>(gptr, x2, Wfc, bfc, out);
}

// Round 10
// 211.663 us; speedup vs baseline: 1.1512x; 1.0223x over previous
//
#include <hip/hip_runtime.h>
#include <hip/hip_bf16.h>
#include <math.h>

#define NN 65536          // nodes
#define NE 196608         // edges (without self loops)
#define ET (NE + NN)      // edges + self loops = 262144
#define NG 2048           // graphs
#define FIN 9
#define DD 128
#define H1 10
#define KK (H1 * DD)      // 1280
#define LRS 0.2f

typedef __attribute__((ext_vector_type(8))) short short8v;
typedef __attribute__((ext_vector_type(4))) float f32x4;

__device__ __forceinline__ float lrelu(float v) { return v >= 0.f ? v : LRS * v; }
__device__ __forceinline__ float eluf(float v)  { return v > 0.f ? v : expm1f(v); }

// float -> bf16 round-to-nearest-even (3 int ops, no libcall)
__device__ __forceinline__ unsigned short f2bf(float f) {
    unsigned int u = __float_as_uint(f);
    u += 0x7FFFu + ((u >> 16) & 1u);
    return (unsigned short)(u >> 16);
}

// ---- setup kernel: packW2 (blocks 0..639) | alpha1+prep (640..895) |
// ---- gptr (896..1151). All branches independent. --------------------------
__global__ __launch_bounds__(256) void setup_kernel(
        const float* __restrict__ W1, const float* __restrict__ W2,
        const float* __restrict__ a_src1, const float* __restrict__ a_dst1,
        const float* __restrict__ x, const int* __restrict__ batch,
        unsigned short* __restrict__ W2p,
        float* __restrict__ as1, float* __restrict__ ad1,
        int* __restrict__ deg, int* __restrict__ gptr) {
    __shared__ float ws_s[FIN * H1], wd_s[FIN * H1];
    const int b = blockIdx.x;
    const int t = threadIdx.x;
    if (b < 640) {
        int idx = b * 256 + t;
        int r  = idx & 7;
        int l  = (idx >> 3) & 63;
        int nt = (idx >> 9) & 7;
        int kt = idx >> 12;
        int k = kt * 32 + ((l >> 4) << 3) + r;
        int n = nt * 16 + (l & 15);
        W2p[idx] = f2bf(W2[(size_t)k * DD + n]);
    } else if (b < 896) {
        if (t < FIN * H1) {
            int f = t / H1, h = t - f * H1;
            float s = 0.f, d = 0.f;
            for (int c = 0; c < DD; ++c) {
                float w = W1[f * KK + h * DD + c];
                s = fmaf(w, a_src1[h * DD + c], s);
                d = fmaf(w, a_dst1[h * DD + c], d);
            }
            ws_s[t] = s;
            wd_s[t] = d;
        }
        __syncthreads();
        int n = (b - 640) * 256 + t;
        float xv[FIN];
#pragma unroll
        for (int f = 0; f < FIN; ++f) xv[f] = x[(size_t)n * FIN + f];
#pragma unroll
        for (int h = 0; h < H1; ++h) {
            float s = 0.f, d = 0.f;
#pragma unroll
            for (int f = 0; f < FIN; ++f) {
                s = fmaf(xv[f], ws_s[f * H1 + h], s);
                d = fmaf(xv[f], wd_s[f * H1 + h], d);
            }
            as1[n * H1 + h] = s;
            ad1[n * H1 + h] = d;
        }
        deg[n] = 0;
    } else {
        int n = (b - 896) * 256 + t;
        int bn = batch[n];
        int bp = (n == 0) ? -1 : batch[n - 1];
        for (int g = bp + 1; g <= bn; ++g) gptr[g] = n;
        if (n == NN - 1) {
            for (int g = bn + 1; g <= NG; ++g) gptr[g] = NN;
        }
    }
}

// ---- CSR build: count / scan / scatter --------------------------------------
__global__ void count_kernel(const int* __restrict__ ei, int* __restrict__ deg) {
    int e = blockIdx.x * 256 + threadIdx.x;
    if (e >= ET) return;
    int d = (e < NE) ? ei[NE + e] : e - NE;
    atomicAdd(&deg[d], 1);
}

__global__ __launch_bounds__(1024) void scan_kernel(const int* __restrict__ deg,
                                                    int* __restrict__ rowptr,
                                                    int* __restrict__ cursor) {
    __shared__ int part[1024];
    int t = threadIdx.x;
    int sum = 0;
    for (int i = 0; i < 64; ++i) sum += deg[t * 64 + i];
    part[t] = sum;
    __syncthreads();
    for (int off = 1; off < 1024; off <<= 1) {
        int v = (t >= off) ? part[t - off] : 0;
        __syncthreads();
        part[t] += v;
        __syncthreads();
    }
    int run = (t == 0) ? 0 : part[t - 1];
    for (int i = 0; i < 64; ++i) {
        int idx = t * 64 + i;
        rowptr[idx] = run;
        cursor[idx] = run;
        run += deg[idx];
    }
    if (t == 1023) rowptr[NN] = run;
}

__global__ void scatter_kernel(const int* __restrict__ ei, int* __restrict__ cursor,
                               int* __restrict__ elist) {
    int e = blockIdx.x * 256 + threadIdx.x;
    if (e >= ET) return;
    int s, d;
    if (e < NE) { s = ei[e]; d = ei[NE + e]; } else { s = d = e - NE; }
    int pos = atomicAdd(&cursor[d], 1);
    elist[pos] = s;
}

// ---- layer-1 aggregation: gather-side, ONLINE softmax, row-major output -----
__global__ void agg1_kernel(const int* __restrict__ rowptr, const int* __restrict__ elist,
                            const float* __restrict__ x,
                            const float* __restrict__ as1, const float* __restrict__ ad1,
                            float* __restrict__ xaggn) {
    int idx = blockIdx.x * 256 + threadIdx.x;     // NN*H1
    if (idx >= NN * H1) return;
    int d = idx / H1, h = idx - d * H1;
    int beg = rowptr[d], end = rowptr[d + 1];
    float adh = ad1[d * H1 + h];
    float m = -INFINITY, den = 0.f;
    float xa[FIN] = {};
    for (int j = beg; j < end; ++j) {
        int s = elist[j];
        float v = lrelu(as1[s * H1 + h] + adh);
        if (v > m) {
            float sc = __expf(m - v);
            den *= sc;
#pragma unroll
            for (int f = 0; f < FIN; ++f) xa[f] *= sc;
            m = v;
        }
        float ex = __expf(v - m);
        den += ex;
        const float* xs = &x[(size_t)s * FIN];
#pragma unroll
        for (int f = 0; f < FIN; ++f) xa[f] = fmaf(ex, xs[f], xa[f]);
    }
    float inv = 1.f / (den + 1e-16f);
    float* o = &xaggn[(size_t)idx * FIN];
#pragma unroll
    for (int f = 0; f < FIN; ++f) o[f] = xa[f] * inv;
}

// ---- fused h2 = elu(xaggn@W1 + b1) @ W2 via MFMA + alpha2 epilogue ----------
// v6: 128x128 block, 8 waves (512 thr). Wave (rh,cq)=(w&1,w>>1) computes
// 64 rows x 32 cols (16 MFMA/step). Halves per-row LDS re-read traffic vs v5.
// Build: thread t makes row t&127, cols (t>>7)*16 (W1 wave-uniform -> s_loads);
// xa hoisted to h-loop. LDS ~63.6 KB -> 2 blocks/CU (16 waves).
__global__ __launch_bounds__(512, 4) void h2_gemm(const float* __restrict__ xaggn,
                                                  const float* __restrict__ W1,
                                                  const float* __restrict__ b1,
                                                  const unsigned short* __restrict__ W2p,
                                                  const float* __restrict__ a_src2,
                                                  const float* __restrict__ a_dst2,
                                                  float* __restrict__ h2,
                                                  float* __restrict__ as2,
                                                  float* __restrict__ ad2) {
    __shared__ float xagg_s[128 * 91];            // 46.6 KB (odd stride: conflict-free)
    __shared__ unsigned short Xs[128 * 64];       // 16 KB, XOR-swizzled 16B granules
    __shared__ float as_s[128], ad_s[128];
    const int t = threadIdx.x;
    const int n0 = blockIdx.x * 128;

    for (int idx = t; idx < 128 * 90; idx += 512) {
        int row = idx / 90, c = idx - row * 90;
        xagg_s[row * 91 + c] = xaggn[(size_t)n0 * 90 + idx];
    }
    if (t < 128) { as_s[t] = 0.f; ad_s[t] = 0.f; }

    const int lane = t & 63;
    const int wvu = __builtin_amdgcn_readfirstlane(t >> 6);   // 0..7
    const int rh  = wvu & 1;                                  // row half (MFMA)
    const int cq  = wvu >> 1;                                 // col quarter (MFMA) == build col group
    const int brow = rh * 64 + lane;                          // build row (= t&127)
    const int rlo = lane & 15, khi = lane >> 4;

    f32x4 acc[4][2];
#pragma unroll
    for (int mt = 0; mt < 4; ++mt)
#pragma unroll
        for (int ntl = 0; ntl < 2; ++ntl)
#pragma unroll
            for (int q = 0; q < 4; ++q) acc[mt][ntl][q] = 0.f;

    __syncthreads();                     // xagg_s staged

    for (int h = 0; h < H1; ++h) {
        float xa[FIN];
#pragma unroll
        for (int f = 0; f < FIN; ++f) xa[f] = xagg_s[brow * 91 + h * FIN + f];
#pragma unroll
        for (int half = 0; half < 2; ++half) {
            const int s = h * 2 + half;
            const int k0 = s << 6;
            // build: 16 cols (wave-uniform W1 -> scalar loads) for this row
            const float* w1s = W1 + (size_t)(k0 + cq * 16);
            const float* b1s = b1 + (k0 + cq * 16);
            float z[16];
#pragma unroll
            for (int c = 0; c < 16; ++c) z[c] = b1s[c];
#pragma unroll
            for (int f = 0; f < FIN; ++f)
#pragma unroll
                for (int c = 0; c < 16; ++c)
                    z[c] = fmaf(xa[f], w1s[(size_t)f * KK + c], z[c]);
            unsigned int pk[8];
#pragma unroll
            for (int p = 0; p < 8; ++p) {
                float lo = z[2 * p], hi = z[2 * p + 1];
                lo = lo > 0.f ? lo : __expf(lo) - 1.f;
                hi = hi > 0.f ? hi : __expf(hi) - 1.f;
                pk[p] = (unsigned int)f2bf(lo) | ((unsigned int)f2bf(hi) << 16);
            }
            __syncthreads();              // prev-iter MFMA reads of Xs done
#pragma unroll
            for (int j = 0; j < 2; ++j) {
                int g = cq * 2 + j;       // granule (8 cols)
                uint4 v = make_uint4(pk[j * 4 + 0], pk[j * 4 + 1], pk[j * 4 + 2], pk[j * 4 + 3]);
                *(uint4*)&Xs[brow * 64 + ((g ^ (brow & 7)) << 3)] = v;
            }
            __syncthreads();
            // MFMA: 2 K-subtiles x 4 row-tiles x 2 col-tiles
#pragma unroll
            for (int ks = 0; ks < 2; ++ks) {
                const int ktabs = s * 2 + ks;
                short8v bfr[2];
#pragma unroll
                for (int ntl = 0; ntl < 2; ++ntl) {
                    const int nt = cq * 2 + ntl;
                    bfr[ntl] = *(const short8v*)&W2p[(((size_t)ktabs * 8 + nt) * 64 + lane) * 8];
                }
#pragma unroll
                for (int mt = 0; mt < 4; ++mt) {
                    const int row2 = rh * 64 + mt * 16 + rlo;
                    const int gk = ks * 4 + khi;
                    short8v af = *(const short8v*)&Xs[row2 * 64 + ((gk ^ (row2 & 7)) << 3)];
                    acc[mt][0] = __builtin_amdgcn_mfma_f32_16x16x32_bf16(af, bfr[0], acc[mt][0], 0, 0, 0);
                    acc[mt][1] = __builtin_amdgcn_mfma_f32_16x16x32_bf16(af, bfr[1], acc[mt][1], 0, 0, 0);
                }
            }
        }
    }

    // C write (fp32): col = cq*32 + ntl*16 + (lane&15), row = rh*64+mt*16+(lane>>4)*4+q
#pragma unroll
    for (int mt = 0; mt < 4; ++mt)
#pragma unroll
        for (int ntl = 0; ntl < 2; ++ntl)
#pragma unroll
            for (int q = 0; q < 4; ++q) {
                int r2 = n0 + rh * 64 + mt * 16 + khi * 4 + q;
                int c2 = cq * 32 + ntl * 16 + rlo;
                h2[(size_t)r2 * DD + c2] = acc[mt][ntl][q];
            }

    // fused alpha2 from fp32 accumulators
    float sp[16], dp[16];
#pragma unroll
    for (int mt = 0; mt < 4; ++mt)
#pragma unroll
        for (int q = 0; q < 4; ++q) {
            float a = 0.f, b = 0.f;
#pragma unroll
            for (int ntl = 0; ntl < 2; ++ntl) {
                int col = cq * 32 + ntl * 16 + rlo;
                float v = acc[mt][ntl][q];
                a = fmaf(v, a_src2[col], a);
                b = fmaf(v, a_dst2[col], b);
            }
            sp[mt * 4 + q] = a;
            dp[mt * 4 + q] = b;
        }
#pragma unroll
    for (int off = 1; off < 16; off <<= 1) {
#pragma unroll
        for (int i = 0; i < 16; ++i) {
            sp[i] += __shfl_xor(sp[i], off);
            dp[i] += __shfl_xor(dp[i], off);
        }
    }
    if (rlo == 0) {
#pragma unroll
        for (int mt = 0; mt < 4; ++mt)
#pragma unroll
            for (int q = 0; q < 4; ++q) {
                atomicAdd(&as_s[rh * 64 + mt * 16 + khi * 4 + q], sp[mt * 4 + q]);
                atomicAdd(&ad_s[rh * 64 + mt * 16 + khi * 4 + q], dp[mt * 4 + q]);
            }
    }
    __syncthreads();
    if (t < 128) {
        as2[n0 + t] = as_s[t];
        ad2[n0 + t] = ad_s[t];
    }
}

// ---- layer-2 aggregation (online softmax, fp32 h2) -> x2 --------------------
__global__ void agg2_kernel(const int* __restrict__ rowptr, const int* __restrict__ elist,
                            const float* __restrict__ h2,
                            const float* __restrict__ as2, const float* __restrict__ ad2,
                            const float* __restrict__ b2, float* __restrict__ x2) {
    int gid = blockIdx.x * 256 + threadIdx.x;
    int n = gid >> 5, lane = gid & 31;
    if (n >= NN) return;
    int beg = rowptr[n], end = rowptr[n + 1];
    float adn = ad2[n];
    float m = -INFINITY, den = 0.f;
    float4 acc = make_float4(0.f, 0.f, 0.f, 0.f);
    for (int j = beg; j < end; ++j) {
        int s = elist[j];
        float v = lrelu(as2[s] + adn);
        if (v > m) {
            float sc = __expf(m - v);
            den *= sc;
            acc.x *= sc; acc.y *= sc; acc.z *= sc; acc.w *= sc;
            m = v;
        }
        float ex = __expf(v - m);
        den += ex;
        float4 hv = *(const float4*)&h2[(size_t)s * DD + lane * 4];
        acc.x = fmaf(ex, hv.x, acc.x);
        acc.y = fmaf(ex, hv.y, acc.y);
        acc.z = fmaf(ex, hv.z, acc.z);
        acc.w = fmaf(ex, hv.w, acc.w);
    }
    float inv = 1.f / (den + 1e-16f);
    float4 bv = *(const float4*)&b2[lane * 4];
    float4 r;
    r.x = eluf(acc.x * inv + bv.x);
    r.y = eluf(acc.y * inv + bv.y);
    r.z = eluf(acc.z * inv + bv.z);
    r.w = eluf(acc.w * inv + bv.w);
    *(float4*)&x2[(size_t)n * DD + lane * 4] = r;
}

// ---- fused pooling + FC: block g pools its node range, then out row g -------
__global__ __launch_bounds__(128) void pool_final_kernel(const int* __restrict__ gptr,
                                                         const float* __restrict__ x2,
                                                         const float* __restrict__ Wfc,
                                                         const float* __restrict__ bfc,
                                                         float* __restrict__ out) {
    __shared__ float pl[DD];
    int g = blockIdx.x;
    int c = threadIdx.x;          // 128 channels
    int beg = gptr[g], end = gptr[g + 1];
    float v = -INFINITY;
    for (int n = beg; n < end; ++n)
        v = fmaxf(v, x2[(size_t)n * DD + c]);
    if (beg == end) v = 0.f;      // empty graph -> 0 (isfinite guard)
    pl[c] = v;
    __syncthreads();
    float acc = bfc[c];
#pragma unroll 8
    for (int k = 0; k < DD; ++k)
        acc = fmaf(pl[k], Wfc[k * DD + c], acc);
    out[(size_t)g * DD + c] = acc > 0.f ? acc : 0.f;
}

extern "C" void kernel_launch(void* const* d_in, const int* in_sizes, int n_in,
                              void* d_out, int out_size, void* d_ws, size_t ws_size,
                              hipStream_t stream) {
    const float* x      = (const float*)d_in[0];
    const int*   ei     = (const int*)d_in[1];
    const int*   batch  = (const int*)d_in[3];
    const float* W1     = (const float*)d_in[4];
    const float* a_src1 = (const float*)d_in[5];
    const float* a_dst1 = (const float*)d_in[6];
    const float* b1     = (const float*)d_in[7];
    const float* W2     = (const float*)d_in[8];
    const float* a_src2 = (const float*)d_in[9];
    const float* a_dst2 = (const float*)d_in[10];
    const float* b2     = (const float*)d_in[11];
    const float* Wfc    = (const float*)d_in[12];
    const float* bfc    = (const float*)d_in[13];
    float* out = (float*)d_out;

    // workspace layout — ~100 MB total
    float* wsf    = (float*)d_ws;
    float* as1    = wsf;                                   // NN*H1
    float* ad1    = as1 + (size_t)NN * H1;                 // NN*H1
    float* xaggn  = ad1 + (size_t)NN * H1;                 // NN*H1*FIN
    float* h2     = xaggn + (size_t)NN * H1 * FIN;         // NN*DD
    float* as2    = h2 + (size_t)NN * DD;                  // NN
    float* ad2    = as2 + NN;                              // NN
    float* x2     = ad2 + NN;                              // NN*DD
    int*   deg    = (int*)(x2 + (size_t)NN * DD);          // NN
    int*   rowptr = deg + NN;                              // NN+1
    int*   cursor = rowptr + NN + 1;                       // NN
    int*   elist  = cursor + NN;                           // ET
    int*   gptr   = elist + ET;                            // NG+1
    size_t off = (size_t)((char*)(gptr + NG + 1) - (char*)d_ws);
    off = (off + 15) & ~(size_t)15;
    unsigned short* W2p = (unsigned short*)((char*)d_ws + off);      // KK*DD bf16

    setup_kernel     <<<1152, 256, 0, stream>>>(W1, W2, a_src1, a_dst1, x, batch,
                                                W2p, as1, ad1, deg, gptr);
    count_kernel     <<<(ET + 255) / 256, 256, 0, stream>>>(ei, deg);
    scan_kernel      <<<1, 1024, 0, stream>>>(deg, rowptr, cursor);
    scatter_kernel   <<<(ET + 255) / 256, 256, 0, stream>>>(ei, cursor, elist);
    agg1_kernel      <<<(NN * H1 + 255) / 256, 256, 0, stream>>>(rowptr, elist, x, as1, ad1, xaggn);
    h2_gemm          <<<NN / 128, 512, 0, stream>>>(xaggn, W1, b1, W2p, a_src2, a_dst2,
                                                    h2, as2, ad2);
    agg2_kernel      <<<(NN * 32) / 256, 256, 0, stream>>>(rowptr, elist, h2, as2, ad2, b2, x2);
    pool_final_kernel<<<NG, 128, 0, stream>>>(gptr, x2, Wfc, bfc, out);
}

// Round 11
// 204.224 us; speedup vs baseline: 1.1931x; 1.0364x over previous
//
#include <hip/hip_runtime.h>
#include <hip/hip_bf16.h>
#include <math.h>

#define NN 65536          // nodes
#define NE 196608         // edges (without self loops)
#define ET (NE + NN)      // edges + self loops = 262144
#define NG 2048           // graphs
#define FIN 9
#define DD 128
#define H1 10
#define KK (H1 * DD)      // 1280
#define LRS 0.2f
#define XSB 36            // xsb row stride (ushorts): 72B rows, ~2-way banks

typedef __attribute__((ext_vector_type(8))) short short8v;
typedef __attribute__((ext_vector_type(4))) float f32x4;

__device__ __forceinline__ float lrelu(float v) { return v >= 0.f ? v : LRS * v; }
__device__ __forceinline__ float eluf(float v)  { return v > 0.f ? v : expm1f(v); }

// float -> bf16 round-to-nearest-even (3 int ops, no libcall)
__device__ __forceinline__ unsigned short f2bf(float f) {
    unsigned int u = __float_as_uint(f);
    u += 0x7FFFu + ((u >> 16) & 1u);
    return (unsigned short)(u >> 16);
}

// ---- setup: packW2 | alpha1+prep | gptr | packW1pT (independent branches) ---
__global__ __launch_bounds__(256) void setup_kernel(
        const float* __restrict__ W1, const float* __restrict__ W2,
        const float* __restrict__ a_src1, const float* __restrict__ a_dst1,
        const float* __restrict__ x, const int* __restrict__ batch,
        unsigned short* __restrict__ W2p, unsigned short* __restrict__ W1pT,
        float* __restrict__ as1, float* __restrict__ ad1,
        int* __restrict__ deg, int* __restrict__ gptr) {
    __shared__ float ws_s[FIN * H1], wd_s[FIN * H1];
    const int b = blockIdx.x;
    const int t = threadIdx.x;
    if (b < 640) {
        // W2 (1280x128 fp32) -> bf16 B-fragment layout
        int idx = b * 256 + t;
        int r  = idx & 7;
        int l  = (idx >> 3) & 63;
        int nt = (idx >> 9) & 7;
        int kt = idx >> 12;
        int k = kt * 32 + ((l >> 4) << 3) + r;
        int n = nt * 16 + (l & 15);
        W2p[idx] = f2bf(W2[(size_t)k * DD + n]);
    } else if (b < 896) {
        if (t < FIN * H1) {
            int f = t / H1, h = t - f * H1;
            float s = 0.f, d = 0.f;
            for (int c = 0; c < DD; ++c) {
                float w = W1[f * KK + h * DD + c];
                s = fmaf(w, a_src1[h * DD + c], s);
                d = fmaf(w, a_dst1[h * DD + c], d);
            }
            ws_s[t] = s;
            wd_s[t] = d;
        }
        __syncthreads();
        int n = (b - 640) * 256 + t;
        float xv[FIN];
#pragma unroll
        for (int f = 0; f < FIN; ++f) xv[f] = x[(size_t)n * FIN + f];
#pragma unroll
        for (int h = 0; h < H1; ++h) {
            float s = 0.f, d = 0.f;
#pragma unroll
            for (int f = 0; f < FIN; ++f) {
                s = fmaf(xv[f], ws_s[f * H1 + h], s);
                d = fmaf(xv[f], wd_s[f * H1 + h], d);
            }
            as1[n * H1 + h] = s;
            ad1[n * H1 + h] = d;
        }
        deg[n] = 0;
    } else if (b < 1152) {
        int n = (b - 896) * 256 + t;
        int bn = batch[n];
        int bp = (n == 0) ? -1 : batch[n - 1];
        for (int g = bp + 1; g <= bn; ++g) gptr[g] = n;
        if (n == NN - 1) {
            for (int g = bn + 1; g <= NG; ++g) gptr[g] = NN;
        }
    } else {
        // W1^T -> bf16 A-fragment layout for the expansion MFMA (K=9 pad 32)
        // W1pT[(((h*8+mt)*64+l)*8+r] = A[c=mt*16+(l&15)][k=(l>>4)*8+r]
        int idx = (b - 1152) * 256 + t;            // 40960 total
        int r  = idx & 7;
        int l  = (idx >> 3) & 63;
        int mt = (idx >> 9) & 7;
        int h  = idx >> 12;
        int f  = ((l >> 4) << 3) + r;
        int c  = mt * 16 + (l & 15);
        W1pT[idx] = (f < FIN) ? f2bf(W1[(size_t)f * KK + h * DD + c]) : (unsigned short)0;
    }
}

// ---- CSR build: count / scan / scatter --------------------------------------
__global__ void count_kernel(const int* __restrict__ ei, int* __restrict__ deg) {
    int e = blockIdx.x * 256 + threadIdx.x;
    if (e >= ET) return;
    int d = (e < NE) ? ei[NE + e] : e - NE;
    atomicAdd(&deg[d], 1);
}

__global__ __launch_bounds__(1024) void scan_kernel(const int* __restrict__ deg,
                                                    int* __restrict__ rowptr,
                                                    int* __restrict__ cursor) {
    __shared__ int part[1024];
    int t = threadIdx.x;
    int sum = 0;
    for (int i = 0; i < 64; ++i) sum += deg[t * 64 + i];
    part[t] = sum;
    __syncthreads();
    for (int off = 1; off < 1024; off <<= 1) {
        int v = (t >= off) ? part[t - off] : 0;
        __syncthreads();
        part[t] += v;
        __syncthreads();
    }
    int run = (t == 0) ? 0 : part[t - 1];
    for (int i = 0; i < 64; ++i) {
        int idx = t * 64 + i;
        rowptr[idx] = run;
        cursor[idx] = run;
        run += deg[idx];
    }
    if (t == 1023) rowptr[NN] = run;
}

__global__ void scatter_kernel(const int* __restrict__ ei, int* __restrict__ cursor,
                               int* __restrict__ elist) {
    int e = blockIdx.x * 256 + threadIdx.x;
    if (e >= ET) return;
    int s, d;
    if (e < NE) { s = ei[e]; d = ei[NE + e]; } else { s = d = e - NE; }
    int pos = atomicAdd(&cursor[d], 1);
    elist[pos] = s;
}

// ---- layer-1 aggregation: online softmax -> bf16 padded rows ----------------
// xaggb[(n*H1+h)*32 + f] bf16: f 0..8 = xagg/den, f 9..31 = 0 (K=32 MFMA pad).
__global__ void agg1_kernel(const int* __restrict__ rowptr, const int* __restrict__ elist,
                            const float* __restrict__ x,
                            const float* __restrict__ as1, const float* __restrict__ ad1,
                            unsigned short* __restrict__ xaggb) {
    int idx = blockIdx.x * 256 + threadIdx.x;     // NN*H1
    if (idx >= NN * H1) return;
    int d = idx / H1, h = idx - d * H1;
    int beg = rowptr[d], end = rowptr[d + 1];
    float adh = ad1[d * H1 + h];
    float m = -INFINITY, den = 0.f;
    float xa[FIN] = {};
    for (int j = beg; j < end; ++j) {
        int s = elist[j];
        float v = lrelu(as1[s * H1 + h] + adh);
        if (v > m) {
            float sc = __expf(m - v);
            den *= sc;
#pragma unroll
            for (int f = 0; f < FIN; ++f) xa[f] *= sc;
            m = v;
        }
        float ex = __expf(v - m);
        den += ex;
        const float* xs = &x[(size_t)s * FIN];
#pragma unroll
        for (int f = 0; f < FIN; ++f) xa[f] = fmaf(ex, xs[f], xa[f]);
    }
    float inv = 1.f / (den + 1e-16f);
    unsigned int w[16];
#pragma unroll
    for (int i = 0; i < 16; ++i) w[i] = 0u;
#pragma unroll
    for (int f = 0; f < FIN; ++f) {
        unsigned int bv = f2bf(xa[f] * inv);
        w[f >> 1] |= bv << ((f & 1) * 16);
    }
    uint4* dst = (uint4*)&xaggb[(size_t)idx * 32];
    dst[0] = make_uint4(w[0], w[1], w[2], w[3]);
    dst[1] = make_uint4(w[4], w[5], w[6], w[7]);
    dst[2] = make_uint4(w[8], w[9], w[10], w[11]);
    dst[3] = make_uint4(w[12], w[13], w[14], w[15]);
}

// ---- h2 = elu(xagg@W1 + b1) @ W2, BOTH matmuls on MFMA + alpha2 epilogue ----
// Per head h: (1) stage xagg head-slice (bf16, K=32-padded) into xsb;
// (2) expansion MFMA D1 = W1h^T(A) * xagg^T(B): lane gets 4 consecutive c for
// one node -> bias+ELU -> pack -> one ds_write_b64 into swizzled Xs;
// (3) main MFMA over the head's K=128. acc persists across heads.
__global__ __launch_bounds__(512, 4) void h2_gemm(
        const unsigned short* __restrict__ xaggb,
        const unsigned short* __restrict__ W1pT,
        const float* __restrict__ b1,
        const unsigned short* __restrict__ W2p,
        const float* __restrict__ a_src2, const float* __restrict__ a_dst2,
        float* __restrict__ h2, float* __restrict__ as2, float* __restrict__ ad2) {
    __shared__ unsigned short Xs[128 * 128];          // 32 KB, XOR-swizzled granules
    __shared__ unsigned short xsb[128 * XSB];         // 9 KB
    __shared__ float as_s[128], ad_s[128];
    const int t = threadIdx.x;
    const int n0 = blockIdx.x * 128;
    const int lane = t & 63;
    const int wvu = __builtin_amdgcn_readfirstlane(t >> 6);   // 0..7
    const int rh = wvu & 1, cq = wvu >> 1;                    // main-GEMM roles
    const int rlo = lane & 15, khi = lane >> 4;
    const int srow = t >> 2, sseg = t & 3;                    // xsb stage roles

    if (t < 128) { as_s[t] = 0.f; ad_s[t] = 0.f; }

    f32x4 acc[4][2];
#pragma unroll
    for (int mt = 0; mt < 4; ++mt)
#pragma unroll
        for (int ntl = 0; ntl < 2; ++ntl)
#pragma unroll
            for (int q = 0; q < 4; ++q) acc[mt][ntl][q] = 0.f;

    for (int h = 0; h < H1; ++h) {
        __syncthreads();                  // prev head's Xs/xsb consumed
        // stage this head's xagg slice: 128 rows x 64 B
        *(uint4*)&xsb[srow * XSB + sseg * 8] =
            *(const uint4*)&xaggb[((size_t)(n0 + srow) * H1 + h) * 32 + sseg * 8];
        __syncthreads();

        // expansion: wave owns c-tile wvu (16 cols of x1 within this head)
        short8v a1 = *(const short8v*)&W1pT[(((size_t)h * 8 + wvu) * 64 + lane) * 8];
        float4 bv4 = *(const float4*)&b1[h * DD + wvu * 16 + khi * 4];
#pragma unroll
        for (int nh = 0; nh < 2; ++nh) {
            f32x4 acc2[4];
#pragma unroll
            for (int j = 0; j < 4; ++j) {
                int nt = nh * 4 + j;
                short8v bfrag = *(const short8v*)&xsb[(nt * 16 + rlo) * XSB + khi * 8];
                f32x4 zz = {0.f, 0.f, 0.f, 0.f};
                acc2[j] = __builtin_amdgcn_mfma_f32_16x16x32_bf16(a1, bfrag, zz, 0, 0, 0);
            }
#pragma unroll
            for (int j = 0; j < 4; ++j) {
                int nt = nh * 4 + j;
                float z0 = acc2[j][0] + bv4.x;
                float z1 = acc2[j][1] + bv4.y;
                float z2 = acc2[j][2] + bv4.z;
                float z3 = acc2[j][3] + bv4.w;
                z0 = z0 > 0.f ? z0 : __expf(z0) - 1.f;
                z1 = z1 > 0.f ? z1 : __expf(z1) - 1.f;
                z2 = z2 > 0.f ? z2 : __expf(z2) - 1.f;
                z3 = z3 > 0.f ? z3 : __expf(z3) - 1.f;
                unsigned int lo = (unsigned int)f2bf(z0) | ((unsigned int)f2bf(z1) << 16);
                unsigned int hi = (unsigned int)f2bf(z2) | ((unsigned int)f2bf(z3) << 16);
                int rown = nt * 16 + rlo;                      // node row in Xs
                int gw = wvu * 2 + (khi >> 1);                 // 16B granule of c-base
                unsigned offu = rown * 128 + (((gw ^ (rown & 15)) << 3) | ((khi & 1) << 2));
                *(uint2*)&Xs[offu] = make_uint2(lo, hi);
            }
        }
        __syncthreads();

        // main GEMM: this head's K=128 (4 sub-K of 32)
#pragma unroll
        for (int ks = 0; ks < 4; ++ks) {
            const int ktabs = h * 4 + ks;
            short8v bfr[2];
#pragma unroll
            for (int ntl = 0; ntl < 2; ++ntl) {
                const int nt = cq * 2 + ntl;
                bfr[ntl] = *(const short8v*)&W2p[(((size_t)ktabs * 8 + nt) * 64 + lane) * 8];
            }
#pragma unroll
            for (int mt = 0; mt < 4; ++mt) {
                const int row2 = rh * 64 + mt * 16 + rlo;
                const int g = ks * 4 + khi;
                unsigned offu = row2 * 128 + ((g ^ (row2 & 15)) << 3);
                short8v af = *(const short8v*)&Xs[offu];
                acc[mt][0] = __builtin_amdgcn_mfma_f32_16x16x32_bf16(af, bfr[0], acc[mt][0], 0, 0, 0);
                acc[mt][1] = __builtin_amdgcn_mfma_f32_16x16x32_bf16(af, bfr[1], acc[mt][1], 0, 0, 0);
            }
        }
    }

    // C write (fp32): col = cq*32+ntl*16+(lane&15), row = rh*64+mt*16+(lane>>4)*4+q
#pragma unroll
    for (int mt = 0; mt < 4; ++mt)
#pragma unroll
        for (int ntl = 0; ntl < 2; ++ntl)
#pragma unroll
            for (int q = 0; q < 4; ++q) {
                int r2 = n0 + rh * 64 + mt * 16 + khi * 4 + q;
                int c2 = cq * 32 + ntl * 16 + rlo;
                h2[(size_t)r2 * DD + c2] = acc[mt][ntl][q];
            }

    // fused alpha2 from fp32 accumulators
    float sp[16], dp[16];
#pragma unroll
    for (int mt = 0; mt < 4; ++mt)
#pragma unroll
        for (int q = 0; q < 4; ++q) {
            float a = 0.f, b = 0.f;
#pragma unroll
            for (int ntl = 0; ntl < 2; ++ntl) {
                int col = cq * 32 + ntl * 16 + rlo;
                float v = acc[mt][ntl][q];
                a = fmaf(v, a_src2[col], a);
                b = fmaf(v, a_dst2[col], b);
            }
            sp[mt * 4 + q] = a;
            dp[mt * 4 + q] = b;
        }
#pragma unroll
    for (int off = 1; off < 16; off <<= 1) {
#pragma unroll
        for (int i = 0; i < 16; ++i) {
            sp[i] += __shfl_xor(sp[i], off);
            dp[i] += __shfl_xor(dp[i], off);
        }
    }
    if (rlo == 0) {
#pragma unroll
        for (int mt = 0; mt < 4; ++mt)
#pragma unroll
            for (int q = 0; q < 4; ++q) {
                atomicAdd(&as_s[rh * 64 + mt * 16 + khi * 4 + q], sp[mt * 4 + q]);
                atomicAdd(&ad_s[rh * 64 + mt * 16 + khi * 4 + q], dp[mt * 4 + q]);
            }
    }
    __syncthreads();
    if (t < 128) {
        as2[n0 + t] = as_s[t];
        ad2[n0 + t] = ad_s[t];
    }
}

// ---- layer-2 aggregation (online softmax, fp32 h2) -> x2 --------------------
__global__ void agg2_kernel(const int* __restrict__ rowptr, const int* __restrict__ elist,
                            const float* __restrict__ h2,
                            const float* __restrict__ as2, const float* __restrict__ ad2,
                            const float* __restrict__ b2, float* __restrict__ x2) {
    int gid = blockIdx.x * 256 + threadIdx.x;
    int n = gid >> 5, lane = gid & 31;
    if (n >= NN) return;
    int beg = rowptr[n], end = rowptr[n + 1];
    float adn = ad2[n];
    float m = -INFINITY, den = 0.f;
    float4 acc = make_float4(0.f, 0.f, 0.f, 0.f);
    for (int j = beg; j < end; ++j) {
        int s = elist[j];
        float v = lrelu(as2[s] + adn);
        if (v > m) {
            float sc = __expf(m - v);
            den *= sc;
            acc.x *= sc; acc.y *= sc; acc.z *= sc; acc.w *= sc;
            m = v;
        }
        float ex = __expf(v - m);
        den += ex;
        float4 hv = *(const float4*)&h2[(size_t)s * DD + lane * 4];
        acc.x = fmaf(ex, hv.x, acc.x);
        acc.y = fmaf(ex, hv.y, acc.y);
        acc.z = fmaf(ex, hv.z, acc.z);
        acc.w = fmaf(ex, hv.w, acc.w);
    }
    float inv = 1.f / (den + 1e-16f);
    float4 bv = *(const float4*)&b2[lane * 4];
    float4 r;
    r.x = eluf(acc.x * inv + bv.x);
    r.y = eluf(acc.y * inv + bv.y);
    r.z = eluf(acc.z * inv + bv.z);
    r.w = eluf(acc.w * inv + bv.w);
    *(float4*)&x2[(size_t)n * DD + lane * 4] = r;
}

// ---- fused pooling + FC: block g pools its node range, then out row g -------
__global__ __launch_bounds__(128) void pool_final_kernel(const int* __restrict__ gptr,
                                                         const float* __restrict__ x2,
                                                         const float* __restrict__ Wfc,
                                                         const float* __restrict__ bfc,
                                                         float* __restrict__ out) {
    __shared__ float pl[DD];
    int g = blockIdx.x;
    int c = threadIdx.x;          // 128 channels
    int beg = gptr[g], end = gptr[g + 1];
    float v = -INFINITY;
    for (int n = beg; n < end; ++n)
        v = fmaxf(v, x2[(size_t)n * DD + c]);
    if (beg == end) v = 0.f;      // empty graph -> 0 (isfinite guard)
    pl[c] = v;
    __syncthreads();
    float acc = bfc[c];
#pragma unroll 8
    for (int k = 0; k < DD; ++k)
        acc = fmaf(pl[k], Wfc[k * DD + c], acc);
    out[(size_t)g * DD + c] = acc > 0.f ? acc : 0.f;
}

extern "C" void kernel_launch(void* const* d_in, const int* in_sizes, int n_in,
                              void* d_out, int out_size, void* d_ws, size_t ws_size,
                              hipStream_t stream) {
    const float* x      = (const float*)d_in[0];
    const int*   ei     = (const int*)d_in[1];
    const int*   batch  = (const int*)d_in[3];
    const float* W1     = (const float*)d_in[4];
    const float* a_src1 = (const float*)d_in[5];
    const float* a_dst1 = (const float*)d_in[6];
    const float* b1     = (const float*)d_in[7];
    const float* W2     = (const float*)d_in[8];
    const float* a_src2 = (const float*)d_in[9];
    const float* a_dst2 = (const float*)d_in[10];
    const float* b2     = (const float*)d_in[11];
    const float* Wfc    = (const float*)d_in[12];
    const float* bfc    = (const float*)d_in[13];
    float* out = (float*)d_out;

    // workspace layout — ~120 MB total
    float* wsf    = (float*)d_ws;
    float* as1    = wsf;                                   // NN*H1
    float* ad1    = as1 + (size_t)NN * H1;                 // NN*H1
    float* h2     = ad1 + (size_t)NN * H1;                 // NN*DD
    float* as2    = h2 + (size_t)NN * DD;                  // NN
    float* ad2    = as2 + NN;                              // NN
    float* x2     = ad2 + NN;                              // NN*DD
    int*   deg    = (int*)(x2 + (size_t)NN * DD);          // NN
    int*   rowptr = deg + NN;                              // NN+1
    int*   cursor = rowptr + NN + 1;                       // NN
    int*   elist  = cursor + NN;                           // ET
    int*   gptr   = elist + ET;                            // NG+1
    size_t off = (size_t)((char*)(gptr + NG + 1) - (char*)d_ws);
    off = (off + 15) & ~(size_t)15;
    unsigned short* W2p   = (unsigned short*)((char*)d_ws + off);    // KK*DD bf16
    unsigned short* W1pT  = W2p + (size_t)KK * DD;                   // 40960 bf16
    unsigned short* xaggb = W1pT + 40960;                            // NN*H1*32 bf16

    setup_kernel     <<<1312, 256, 0, stream>>>(W1, W2, a_src1, a_dst1, x, batch,
                                                W2p, W1pT, as1, ad1, deg, gptr);
    count_kernel     <<<(ET + 255) / 256, 256, 0, stream>>>(ei, deg);
    scan_kernel      <<<1, 1024, 0, stream>>>(deg, rowptr, cursor);
    scatter_kernel   <<<(ET + 255) / 256, 256, 0, stream>>>(ei, cursor, elist);
    agg1_kernel      <<<(NN * H1 + 255) / 256, 256, 0, stream>>>(rowptr, elist, x, as1, ad1, xaggb);
    h2_gemm          <<<NN / 128, 512, 0, stream>>>(xaggb, W1pT, b1, W2p, a_src2, a_dst2,
                                                    h2, as2, ad2);
    agg2_kernel      <<<(NN * 32) / 256, 256, 0, stream>>>(rowptr, elist, h2, as2, ad2, b2, x2);
    pool_final_kernel<<<NG, 128, 0, stream>>>(gptr, x2, Wfc, bfc, out);
}

// Round 12
// 201.598 us; speedup vs baseline: 1.2086x; 1.0130x over previous
//
#include <hip/hip_runtime.h>
#include <hip/hip_bf16.h>
#include <math.h>

#define NN 65536          // nodes
#define NE 196608         // edges (without self loops)
#define ET (NE + NN)      // edges + self loops = 262144
#define NG 2048           // graphs
#define FIN 9
#define DD 128
#define H1 10
#define KK (H1 * DD)      // 1280
#define LRS 0.2f
#define XSB 36            // xsb row stride (ushorts): 72B rows

typedef __attribute__((ext_vector_type(8))) short short8v;
typedef __attribute__((ext_vector_type(4))) float f32x4;

__device__ __forceinline__ float lrelu(float v) { return v >= 0.f ? v : LRS * v; }
__device__ __forceinline__ float eluf(float v)  { return v > 0.f ? v : expm1f(v); }

// float -> bf16 round-to-nearest-even (3 int ops, no libcall)
__device__ __forceinline__ unsigned short f2bf(float f) {
    unsigned int u = __float_as_uint(f);
    u += 0x7FFFu + ((u >> 16) & 1u);
    return (unsigned short)(u >> 16);
}

// ---- setup: packW2 | alpha1+prep | gptr | packW1pT (independent branches) ---
__global__ __launch_bounds__(256) void setup_kernel(
        const float* __restrict__ W1, const float* __restrict__ W2,
        const float* __restrict__ a_src1, const float* __restrict__ a_dst1,
        const float* __restrict__ x, const int* __restrict__ batch,
        unsigned short* __restrict__ W2p, unsigned short* __restrict__ W1pT,
        float* __restrict__ as1, float* __restrict__ ad1,
        int* __restrict__ deg, int* __restrict__ gptr) {
    __shared__ float ws_s[FIN * H1], wd_s[FIN * H1];
    const int b = blockIdx.x;
    const int t = threadIdx.x;
    if (b < 640) {
        // W2 (1280x128 fp32) -> bf16 B-fragment layout
        int idx = b * 256 + t;
        int r  = idx & 7;
        int l  = (idx >> 3) & 63;
        int nt = (idx >> 9) & 7;
        int kt = idx >> 12;
        int k = kt * 32 + ((l >> 4) << 3) + r;
        int n = nt * 16 + (l & 15);
        W2p[idx] = f2bf(W2[(size_t)k * DD + n]);
    } else if (b < 896) {
        if (t < FIN * H1) {
            int f = t / H1, h = t - f * H1;
            float s = 0.f, d = 0.f;
            for (int c = 0; c < DD; ++c) {
                float w = W1[f * KK + h * DD + c];
                s = fmaf(w, a_src1[h * DD + c], s);
                d = fmaf(w, a_dst1[h * DD + c], d);
            }
            ws_s[t] = s;
            wd_s[t] = d;
        }
        __syncthreads();
        int n = (b - 640) * 256 + t;
        float xv[FIN];
#pragma unroll
        for (int f = 0; f < FIN; ++f) xv[f] = x[(size_t)n * FIN + f];
#pragma unroll
        for (int h = 0; h < H1; ++h) {
            float s = 0.f, d = 0.f;
#pragma unroll
            for (int f = 0; f < FIN; ++f) {
                s = fmaf(xv[f], ws_s[f * H1 + h], s);
                d = fmaf(xv[f], wd_s[f * H1 + h], d);
            }
            as1[n * H1 + h] = s;
            ad1[n * H1 + h] = d;
        }
        deg[n] = 0;
    } else if (b < 1152) {
        int n = (b - 896) * 256 + t;
        int bn = batch[n];
        int bp = (n == 0) ? -1 : batch[n - 1];
        for (int g = bp + 1; g <= bn; ++g) gptr[g] = n;
        if (n == NN - 1) {
            for (int g = bn + 1; g <= NG; ++g) gptr[g] = NN;
        }
    } else {
        // W1^T -> bf16 A-fragment layout for the expansion MFMA (K=9 pad 32)
        int idx = (b - 1152) * 256 + t;            // 40960 total
        int r  = idx & 7;
        int l  = (idx >> 3) & 63;
        int mt = (idx >> 9) & 7;
        int h  = idx >> 12;
        int f  = ((l >> 4) << 3) + r;
        int c  = mt * 16 + (l & 15);
        W1pT[idx] = (f < FIN) ? f2bf(W1[(size_t)f * KK + h * DD + c]) : (unsigned short)0;
    }
}

// ---- CSR build: count / scan / scatter --------------------------------------
__global__ void count_kernel(const int* __restrict__ ei, int* __restrict__ deg) {
    int e = blockIdx.x * 256 + threadIdx.x;
    if (e >= ET) return;
    int d = (e < NE) ? ei[NE + e] : e - NE;
    atomicAdd(&deg[d], 1);
}

__global__ __launch_bounds__(1024) void scan_kernel(const int* __restrict__ deg,
                                                    int* __restrict__ rowptr,
                                                    int* __restrict__ cursor) {
    __shared__ int part[1024];
    int t = threadIdx.x;
    int sum = 0;
    for (int i = 0; i < 64; ++i) sum += deg[t * 64 + i];
    part[t] = sum;
    __syncthreads();
    for (int off = 1; off < 1024; off <<= 1) {
        int v = (t >= off) ? part[t - off] : 0;
        __syncthreads();
        part[t] += v;
        __syncthreads();
    }
    int run = (t == 0) ? 0 : part[t - 1];
    for (int i = 0; i < 64; ++i) {
        int idx = t * 64 + i;
        rowptr[idx] = run;
        cursor[idx] = run;
        run += deg[idx];
    }
    if (t == 1023) rowptr[NN] = run;
}

__global__ void scatter_kernel(const int* __restrict__ ei, int* __restrict__ cursor,
                               int* __restrict__ elist) {
    int e = blockIdx.x * 256 + threadIdx.x;
    if (e >= ET) return;
    int s, d;
    if (e < NE) { s = ei[e]; d = ei[NE + e]; } else { s = d = e - NE; }
    int pos = atomicAdd(&cursor[d], 1);
    elist[pos] = s;
}

// ---- layer-1 aggregation: online softmax -> bf16 padded rows ----------------
// xaggb[(n*H1+h)*32 + f] bf16: f 0..8 = xagg/den, f 9..31 = 0 (K=32 MFMA pad).
__global__ void agg1_kernel(const int* __restrict__ rowptr, const int* __restrict__ elist,
                            const float* __restrict__ x,
                            const float* __restrict__ as1, const float* __restrict__ ad1,
                            unsigned short* __restrict__ xaggb) {
    int idx = blockIdx.x * 256 + threadIdx.x;     // NN*H1
    if (idx >= NN * H1) return;
    int d = idx / H1, h = idx - d * H1;
    int beg = rowptr[d], end = rowptr[d + 1];
    float adh = ad1[d * H1 + h];
    float m = -INFINITY, den = 0.f;
    float xa[FIN] = {};
    for (int j = beg; j < end; ++j) {
        int s = elist[j];
        float v = lrelu(as1[s * H1 + h] + adh);
        if (v > m) {
            float sc = __expf(m - v);
            den *= sc;
#pragma unroll
            for (int f = 0; f < FIN; ++f) xa[f] *= sc;
            m = v;
        }
        float ex = __expf(v - m);
        den += ex;
        const float* xs = &x[(size_t)s * FIN];
#pragma unroll
        for (int f = 0; f < FIN; ++f) xa[f] = fmaf(ex, xs[f], xa[f]);
    }
    float inv = 1.f / (den + 1e-16f);
    unsigned int w[16];
#pragma unroll
    for (int i = 0; i < 16; ++i) w[i] = 0u;
#pragma unroll
    for (int f = 0; f < FIN; ++f) {
        unsigned int bv = f2bf(xa[f] * inv);
        w[f >> 1] |= bv << ((f & 1) * 16);
    }
    uint4* dst = (uint4*)&xaggb[(size_t)idx * 32];
    dst[0] = make_uint4(w[0], w[1], w[2], w[3]);
    dst[1] = make_uint4(w[4], w[5], w[6], w[7]);
    dst[2] = make_uint4(w[8], w[9], w[10], w[11]);
    dst[3] = make_uint4(w[12], w[13], w[14], w[15]);
}

// ---- h2 = elu(xagg@W1 + b1) @ W2, BOTH matmuls on MFMA + alpha2 epilogue ----
// v8: Xs split into two 64-col halves with v6's conflict-free swizzle
// (128B rows, g^row&7); xsb double-buffered (stage head h+1 during head h's
// main GEMM) -> 2 barriers/head.
__global__ __launch_bounds__(512, 4) void h2_gemm(
        const unsigned short* __restrict__ xaggb,
        const unsigned short* __restrict__ W1pT,
        const float* __restrict__ b1,
        const unsigned short* __restrict__ W2p,
        const float* __restrict__ a_src2, const float* __restrict__ a_dst2,
        float* __restrict__ h2, float* __restrict__ as2, float* __restrict__ ad2) {
    __shared__ unsigned short Xs0[128 * 64];          // 16 KB, v6 swizzle
    __shared__ unsigned short Xs1[128 * 64];          // 16 KB
    __shared__ unsigned short xsb[2][128 * XSB];      // 2 x 9 KB
    __shared__ float as_s[128], ad_s[128];
    const int t = threadIdx.x;
    const int n0 = blockIdx.x * 128;
    const int lane = t & 63;
    const int wvu = __builtin_amdgcn_readfirstlane(t >> 6);   // 0..7
    const int rh = wvu & 1, cq = wvu >> 1;                    // main-GEMM roles
    const int rlo = lane & 15, khi = lane >> 4;
    const int srow = t >> 2, sseg = t & 3;                    // xsb stage roles

    if (t < 128) { as_s[t] = 0.f; ad_s[t] = 0.f; }

    f32x4 acc[4][2];
#pragma unroll
    for (int mt = 0; mt < 4; ++mt)
#pragma unroll
        for (int ntl = 0; ntl < 2; ++ntl)
#pragma unroll
            for (int q = 0; q < 4; ++q) acc[mt][ntl][q] = 0.f;

    // prologue: stage head 0's xagg slice
    *(uint4*)&xsb[0][srow * XSB + sseg * 8] =
        *(const uint4*)&xaggb[((size_t)(n0 + srow) * H1 + 0) * 32 + sseg * 8];

    for (int h = 0; h < H1; ++h) {
        const int cur = h & 1;
        __syncthreads();                  // xsb[cur] staged; prev Xs reads done

        // expansion: wave owns c-tile wvu (16 cols of x1 within this head)
        short8v a1 = *(const short8v*)&W1pT[(((size_t)h * 8 + wvu) * 64 + lane) * 8];
        float4 bv4 = *(const float4*)&b1[h * DD + wvu * 16 + khi * 4];
        unsigned short* XsW = (wvu >> 2) ? Xs1 : Xs0;          // write half
        const int gw7 = (wvu * 2 + (khi >> 1)) & 7;            // granule in half
#pragma unroll
        for (int nh = 0; nh < 2; ++nh) {
            f32x4 acc2[4];
#pragma unroll
            for (int j = 0; j < 4; ++j) {
                int nt = nh * 4 + j;
                short8v bfrag = *(const short8v*)&xsb[cur][(nt * 16 + rlo) * XSB + khi * 8];
                f32x4 zz = {0.f, 0.f, 0.f, 0.f};
                acc2[j] = __builtin_amdgcn_mfma_f32_16x16x32_bf16(a1, bfrag, zz, 0, 0, 0);
            }
#pragma unroll
            for (int j = 0; j < 4; ++j) {
                int nt = nh * 4 + j;
                float z0 = acc2[j][0] + bv4.x;
                float z1 = acc2[j][1] + bv4.y;
                float z2 = acc2[j][2] + bv4.z;
                float z3 = acc2[j][3] + bv4.w;
                z0 = z0 > 0.f ? z0 : __expf(z0) - 1.f;
                z1 = z1 > 0.f ? z1 : __expf(z1) - 1.f;
                z2 = z2 > 0.f ? z2 : __expf(z2) - 1.f;
                z3 = z3 > 0.f ? z3 : __expf(z3) - 1.f;
                unsigned int lo = (unsigned int)f2bf(z0) | ((unsigned int)f2bf(z1) << 16);
                unsigned int hi = (unsigned int)f2bf(z2) | ((unsigned int)f2bf(z3) << 16);
                int rown = nt * 16 + rlo;                      // node row
                unsigned offu = rown * 64 + (((gw7 ^ (rown & 7)) << 3) | ((khi & 1) << 2));
                *(uint2*)&XsW[offu] = make_uint2(lo, hi);
            }
        }
        __syncthreads();                  // Xs visible

        // stage next head's xagg slice into the other xsb buffer (overlaps GEMM)
        if (h + 1 < H1) {
            *(uint4*)&xsb[cur ^ 1][srow * XSB + sseg * 8] =
                *(const uint4*)&xaggb[((size_t)(n0 + srow) * H1 + (h + 1)) * 32 + sseg * 8];
        }

        // main GEMM: this head's K=128 (4 sub-K of 32; ks<2 -> Xs0, ks>=2 -> Xs1)
#pragma unroll
        for (int ks = 0; ks < 4; ++ks) {
            const int ktabs = h * 4 + ks;
            const unsigned short* XsR = (ks >> 1) ? Xs1 : Xs0;
            const int g7 = (ks & 1) * 4 + khi;                 // granule in half
            short8v bfr[2];
#pragma unroll
            for (int ntl = 0; ntl < 2; ++ntl) {
                const int nt = cq * 2 + ntl;
                bfr[ntl] = *(const short8v*)&W2p[(((size_t)ktabs * 8 + nt) * 64 + lane) * 8];
            }
#pragma unroll
            for (int mt = 0; mt < 4; ++mt) {
                const int row2 = rh * 64 + mt * 16 + rlo;
                unsigned offu = row2 * 64 + ((g7 ^ (row2 & 7)) << 3);
                short8v af = *(const short8v*)&XsR[offu];
                acc[mt][0] = __builtin_amdgcn_mfma_f32_16x16x32_bf16(af, bfr[0], acc[mt][0], 0, 0, 0);
                acc[mt][1] = __builtin_amdgcn_mfma_f32_16x16x32_bf16(af, bfr[1], acc[mt][1], 0, 0, 0);
            }
        }
    }

    // C write (fp32): col = cq*32+ntl*16+(lane&15), row = rh*64+mt*16+(lane>>4)*4+q
#pragma unroll
    for (int mt = 0; mt < 4; ++mt)
#pragma unroll
        for (int ntl = 0; ntl < 2; ++ntl)
#pragma unroll
            for (int q = 0; q < 4; ++q) {
                int r2 = n0 + rh * 64 + mt * 16 + khi * 4 + q;
                int c2 = cq * 32 + ntl * 16 + rlo;
                h2[(size_t)r2 * DD + c2] = acc[mt][ntl][q];
            }

    // fused alpha2 from fp32 accumulators
    float sp[16], dp[16];
#pragma unroll
    for (int mt = 0; mt < 4; ++mt)
#pragma unroll
        for (int q = 0; q < 4; ++q) {
            float a = 0.f, b = 0.f;
#pragma unroll
            for (int ntl = 0; ntl < 2; ++ntl) {
                int col = cq * 32 + ntl * 16 + rlo;
                float v = acc[mt][ntl][q];
                a = fmaf(v, a_src2[col], a);
                b = fmaf(v, a_dst2[col], b);
            }
            sp[mt * 4 + q] = a;
            dp[mt * 4 + q] = b;
        }
#pragma unroll
    for (int off = 1; off < 16; off <<= 1) {
#pragma unroll
        for (int i = 0; i < 16; ++i) {
            sp[i] += __shfl_xor(sp[i], off);
            dp[i] += __shfl_xor(dp[i], off);
        }
    }
    if (rlo == 0) {
#pragma unroll
        for (int mt = 0; mt < 4; ++mt)
#pragma unroll
            for (int q = 0; q < 4; ++q) {
                atomicAdd(&as_s[rh * 64 + mt * 16 + khi * 4 + q], sp[mt * 4 + q]);
                atomicAdd(&ad_s[rh * 64 + mt * 16 + khi * 4 + q], dp[mt * 4 + q]);
            }
    }
    __syncthreads();
    if (t < 128) {
        as2[n0 + t] = as_s[t];
        ad2[n0 + t] = ad_s[t];
    }
}

// ---- layer-2 aggregation (online softmax, fp32 h2) -> x2 --------------------
__global__ void agg2_kernel(const int* __restrict__ rowptr, const int* __restrict__ elist,
                            const float* __restrict__ h2,
                            const float* __restrict__ as2, const float* __restrict__ ad2,
                            const float* __restrict__ b2, float* __restrict__ x2) {
    int gid = blockIdx.x * 256 + threadIdx.x;
    int n = gid >> 5, lane = gid & 31;
    if (n >= NN) return;
    int beg = rowptr[n], end = rowptr[n + 1];
    float adn = ad2[n];
    float m = -INFINITY, den = 0.f;
    float4 acc = make_float4(0.f, 0.f, 0.f, 0.f);
    for (int j = beg; j < end; ++j) {
        int s = elist[j];
        float v = lrelu(as2[s] + adn);
        if (v > m) {
            float sc = __expf(m - v);
            den *= sc;
            acc.x *= sc; acc.y *= sc; acc.z *= sc; acc.w *= sc;
            m = v;
        }
        float ex = __expf(v - m);
        den += ex;
        float4 hv = *(const float4*)&h2[(size_t)s * DD + lane * 4];
        acc.x = fmaf(ex, hv.x, acc.x);
        acc.y = fmaf(ex, hv.y, acc.y);
        acc.z = fmaf(ex, hv.z, acc.z);
        acc.w = fmaf(ex, hv.w, acc.w);
    }
    float inv = 1.f / (den + 1e-16f);
    float4 bv = *(const float4*)&b2[lane * 4];
    float4 r;
    r.x = eluf(acc.x * inv + bv.x);
    r.y = eluf(acc.y * inv + bv.y);
    r.z = eluf(acc.z * inv + bv.z);
    r.w = eluf(acc.w * inv + bv.w);
    *(float4*)&x2[(size_t)n * DD + lane * 4] = r;
}

// ---- fused pooling + FC: block g pools its node range, then out row g -------
__global__ __launch_bounds__(128) void pool_final_kernel(const int* __restrict__ gptr,
                                                         const float* __restrict__ x2,
                                                         const float* __restrict__ Wfc,
                                                         const float* __restrict__ bfc,
                                                         float* __restrict__ out) {
    __shared__ float pl[DD];
    int g = blockIdx.x;
    int c = threadIdx.x;          // 128 channels
    int beg = gptr[g], end = gptr[g + 1];
    float v = -INFINITY;
    for (int n = beg; n < end; ++n)
        v = fmaxf(v, x2[(size_t)n * DD + c]);
    if (beg == end) v = 0.f;      // empty graph -> 0 (isfinite guard)
    pl[c] = v;
    __syncthreads();
    float acc = bfc[c];
#pragma unroll 8
    for (int k = 0; k < DD; ++k)
        acc = fmaf(pl[k], Wfc[k * DD + c], acc);
    out[(size_t)g * DD + c] = acc > 0.f ? acc : 0.f;
}

extern "C" void kernel_launch(void* const* d_in, const int* in_sizes, int n_in,
                              void* d_out, int out_size, void* d_ws, size_t ws_size,
                              hipStream_t stream) {
    const float* x      = (const float*)d_in[0];
    const int*   ei     = (const int*)d_in[1];
    const int*   batch  = (const int*)d_in[3];
    const float* W1     = (const float*)d_in[4];
    const float* a_src1 = (const float*)d_in[5];
    const float* a_dst1 = (const float*)d_in[6];
    const float* b1     = (const float*)d_in[7];
    const float* W2     = (const float*)d_in[8];
    const float* a_src2 = (const float*)d_in[9];
    const float* a_dst2 = (const float*)d_in[10];
    const float* b2     = (const float*)d_in[11];
    const float* Wfc    = (const float*)d_in[12];
    const float* bfc    = (const float*)d_in[13];
    float* out = (float*)d_out;

    // workspace layout — ~120 MB total
    float* wsf    = (float*)d_ws;
    float* as1    = wsf;                                   // NN*H1
    float* ad1    = as1 + (size_t)NN * H1;                 // NN*H1
    float* h2     = ad1 + (size_t)NN * H1;                 // NN*DD
    float* as2    = h2 + (size_t)NN * DD;                  // NN
    float* ad2    = as2 + NN;                              // NN
    float* x2     = ad2 + NN;                              // NN*DD
    int*   deg    = (int*)(x2 + (size_t)NN * DD);          // NN
    int*   rowptr = deg + NN;                              // NN+1
    int*   cursor = rowptr + NN + 1;                       // NN
    int*   elist  = cursor + NN;                           // ET
    int*   gptr   = elist + ET;                            // NG+1
    size_t off = (size_t)((char*)(gptr + NG + 1) - (char*)d_ws);
    off = (off + 15) & ~(size_t)15;
    unsigned short* W2p   = (unsigned short*)((char*)d_ws + off);    // KK*DD bf16
    unsigned short* W1pT  = W2p + (size_t)KK * DD;                   // 40960 bf16
    unsigned short* xaggb = W1pT + 40960;                            // NN*H1*32 bf16

    setup_kernel     <<<1312, 256, 0, stream>>>(W1, W2, a_src1, a_dst1, x, batch,
                                                W2p, W1pT, as1, ad1, deg, gptr);
    count_kernel     <<<(ET + 255) / 256, 256, 0, stream>>>(ei, deg);
    scan_kernel      <<<1, 1024, 0, stream>>>(deg, rowptr, cursor);
    scatter_kernel   <<<(ET + 255) / 256, 256, 0, stream>>>(ei, cursor, elist);
    agg1_kernel      <<<(NN * H1 + 255) / 256, 256, 0, stream>>>(rowptr, elist, x, as1, ad1, xaggb);
    h2_gemm          <<<NN / 128, 512, 0, stream>>>(xaggb, W1pT, b1, W2p, a_src2, a_dst2,
                                                    h2, as2, ad2);
    agg2_kernel      <<<(NN * 32) / 256, 256, 0, stream>>>(rowptr, elist, h2, as2, ad2, b2, x2);
    pool_final_kernel<<<NG, 128, 0, stream>>>(gptr, x2, Wfc, bfc, out);
}

// Round 13
// 201.573 us; speedup vs baseline: 1.2088x; 1.0001x over previous
//
#include <hip/hip_runtime.h>
#include <hip/hip_bf16.h>
#include <math.h>

#define NN 65536          // nodes
#define NE 196608         // edges (without self loops)
#define ET (NE + NN)      // edges + self loops = 262144
#define NG 2048           // graphs
#define FIN 9
#define DD 128
#define H1 10
#define KK (H1 * DD)      // 1280
#define LRS 0.2f
#define XSB 36            // xsb row stride (ushorts): 72B rows

typedef __attribute__((ext_vector_type(8))) short short8v;
typedef __attribute__((ext_vector_type(4))) float f32x4;

__device__ __forceinline__ float lrelu(float v) { return v >= 0.f ? v : LRS * v; }
__device__ __forceinline__ float eluf(float v)  { return v > 0.f ? v : expm1f(v); }

// float -> bf16 round-to-nearest-even (3 int ops, no libcall)
__device__ __forceinline__ unsigned short f2bf(float f) {
    unsigned int u = __float_as_uint(f);
    u += 0x7FFFu + ((u >> 16) & 1u);
    return (unsigned short)(u >> 16);
}
__device__ __forceinline__ float bf2f(unsigned short s) {
    return __uint_as_float((unsigned int)s << 16);
}

// ---- setup: packW2 | alpha1+prep | gptr | packW1pT (independent branches) ---
__global__ __launch_bounds__(256) void setup_kernel(
        const float* __restrict__ W1, const float* __restrict__ W2,
        const float* __restrict__ a_src1, const float* __restrict__ a_dst1,
        const float* __restrict__ x, const int* __restrict__ batch,
        unsigned short* __restrict__ W2p, unsigned short* __restrict__ W1pT,
        float* __restrict__ as1, float* __restrict__ ad1,
        int* __restrict__ deg, int* __restrict__ gptr) {
    __shared__ float ws_s[FIN * H1], wd_s[FIN * H1];
    const int b = blockIdx.x;
    const int t = threadIdx.x;
    if (b < 640) {
        // W2 (1280x128 fp32) -> bf16 B-fragment layout
        int idx = b * 256 + t;
        int r  = idx & 7;
        int l  = (idx >> 3) & 63;
        int nt = (idx >> 9) & 7;
        int kt = idx >> 12;
        int k = kt * 32 + ((l >> 4) << 3) + r;
        int n = nt * 16 + (l & 15);
        W2p[idx] = f2bf(W2[(size_t)k * DD + n]);
    } else if (b < 896) {
        if (t < FIN * H1) {
            int f = t / H1, h = t - f * H1;
            float s = 0.f, d = 0.f;
            for (int c = 0; c < DD; ++c) {
                float w = W1[f * KK + h * DD + c];
                s = fmaf(w, a_src1[h * DD + c], s);
                d = fmaf(w, a_dst1[h * DD + c], d);
            }
            ws_s[t] = s;
            wd_s[t] = d;
        }
        __syncthreads();
        int n = (b - 640) * 256 + t;
        float xv[FIN];
#pragma unroll
        for (int f = 0; f < FIN; ++f) xv[f] = x[(size_t)n * FIN + f];
#pragma unroll
        for (int h = 0; h < H1; ++h) {
            float s = 0.f, d = 0.f;
#pragma unroll
            for (int f = 0; f < FIN; ++f) {
                s = fmaf(xv[f], ws_s[f * H1 + h], s);
                d = fmaf(xv[f], wd_s[f * H1 + h], d);
            }
            as1[n * H1 + h] = s;
            ad1[n * H1 + h] = d;
        }
        deg[n] = 0;
    } else if (b < 1152) {
        int n = (b - 896) * 256 + t;
        int bn = batch[n];
        int bp = (n == 0) ? -1 : batch[n - 1];
        for (int g = bp + 1; g <= bn; ++g) gptr[g] = n;
        if (n == NN - 1) {
            for (int g = bn + 1; g <= NG; ++g) gptr[g] = NN;
        }
    } else {
        // W1^T -> bf16 A-fragment layout for the expansion MFMA (K=9 pad 32)
        int idx = (b - 1152) * 256 + t;            // 40960 total
        int r  = idx & 7;
        int l  = (idx >> 3) & 63;
        int mt = (idx >> 9) & 7;
        int h  = idx >> 12;
        int f  = ((l >> 4) << 3) + r;
        int c  = mt * 16 + (l & 15);
        W1pT[idx] = (f < FIN) ? f2bf(W1[(size_t)f * KK + h * DD + c]) : (unsigned short)0;
    }
}

// ---- CSR build: count / scan / scatter --------------------------------------
__global__ void count_kernel(const int* __restrict__ ei, int* __restrict__ deg) {
    int e = blockIdx.x * 256 + threadIdx.x;
    if (e >= ET) return;
    int d = (e < NE) ? ei[NE + e] : e - NE;
    atomicAdd(&deg[d], 1);
}

__global__ __launch_bounds__(1024) void scan_kernel(const int* __restrict__ deg,
                                                    int* __restrict__ rowptr,
                                                    int* __restrict__ cursor) {
    __shared__ int part[1024];
    int t = threadIdx.x;
    int sum = 0;
    for (int i = 0; i < 64; ++i) sum += deg[t * 64 + i];
    part[t] = sum;
    __syncthreads();
    for (int off = 1; off < 1024; off <<= 1) {
        int v = (t >= off) ? part[t - off] : 0;
        __syncthreads();
        part[t] += v;
        __syncthreads();
    }
    int run = (t == 0) ? 0 : part[t - 1];
    for (int i = 0; i < 64; ++i) {
        int idx = t * 64 + i;
        rowptr[idx] = run;
        cursor[idx] = run;
        run += deg[idx];
    }
    if (t == 1023) rowptr[NN] = run;
}

__global__ void scatter_kernel(const int* __restrict__ ei, int* __restrict__ cursor,
                               int* __restrict__ elist) {
    int e = blockIdx.x * 256 + threadIdx.x;
    if (e >= ET) return;
    int s, d;
    if (e < NE) { s = ei[e]; d = ei[NE + e]; } else { s = d = e - NE; }
    int pos = atomicAdd(&cursor[d], 1);
    elist[pos] = s;
}

// ---- layer-1 aggregation: online softmax -> bf16 padded rows ----------------
// xaggb[(n*H1+h)*32 + f] bf16: f 0..8 = xagg/den, f 9..31 = 0 (K=32 MFMA pad).
__global__ void agg1_kernel(const int* __restrict__ rowptr, const int* __restrict__ elist,
                            const float* __restrict__ x,
                            const float* __restrict__ as1, const float* __restrict__ ad1,
                            unsigned short* __restrict__ xaggb) {
    int idx = blockIdx.x * 256 + threadIdx.x;     // NN*H1
    if (idx >= NN * H1) return;
    int d = idx / H1, h = idx - d * H1;
    int beg = rowptr[d], end = rowptr[d + 1];
    float adh = ad1[d * H1 + h];
    float m = -INFINITY, den = 0.f;
    float xa[FIN] = {};
    for (int j = beg; j < end; ++j) {
        int s = elist[j];
        float v = lrelu(as1[s * H1 + h] + adh);
        if (v > m) {
            float sc = __expf(m - v);
            den *= sc;
#pragma unroll
            for (int f = 0; f < FIN; ++f) xa[f] *= sc;
            m = v;
        }
        float ex = __expf(v - m);
        den += ex;
        const float* xs = &x[(size_t)s * FIN];
#pragma unroll
        for (int f = 0; f < FIN; ++f) xa[f] = fmaf(ex, xs[f], xa[f]);
    }
    float inv = 1.f / (den + 1e-16f);
    unsigned int w[16];
#pragma unroll
    for (int i = 0; i < 16; ++i) w[i] = 0u;
#pragma unroll
    for (int f = 0; f < FIN; ++f) {
        unsigned int bv = f2bf(xa[f] * inv);
        w[f >> 1] |= bv << ((f & 1) * 16);
    }
    uint4* dst = (uint4*)&xaggb[(size_t)idx * 32];
    dst[0] = make_uint4(w[0], w[1], w[2], w[3]);
    dst[1] = make_uint4(w[4], w[5], w[6], w[7]);
    dst[2] = make_uint4(w[8], w[9], w[10], w[11]);
    dst[3] = make_uint4(w[12], w[13], w[14], w[15]);
}

// ---- h2 = elu(xagg@W1 + b1) @ W2, BOTH matmuls on MFMA + alpha2 epilogue ----
// v9: epilogue stages the fp32 acc tile as bf16 into the (now dead) Xs
// buffers, then one coalesced uint4 copy to h2b (16.8 MB vs 33.5 MB fp32).
__global__ __launch_bounds__(512, 4) void h2_gemm(
        const unsigned short* __restrict__ xaggb,
        const unsigned short* __restrict__ W1pT,
        const float* __restrict__ b1,
        const unsigned short* __restrict__ W2p,
        const float* __restrict__ a_src2, const float* __restrict__ a_dst2,
        unsigned short* __restrict__ h2b, float* __restrict__ as2,
        float* __restrict__ ad2) {
    __shared__ unsigned short Xs0[128 * 64];          // 16 KB, v6 swizzle
    __shared__ unsigned short Xs1[128 * 64];          // 16 KB
    __shared__ unsigned short xsb[2][128 * XSB];      // 2 x 9 KB
    __shared__ float as_s[128], ad_s[128];
    const int t = threadIdx.x;
    const int n0 = blockIdx.x * 128;
    const int lane = t & 63;
    const int wvu = __builtin_amdgcn_readfirstlane(t >> 6);   // 0..7
    const int rh = wvu & 1, cq = wvu >> 1;                    // main-GEMM roles
    const int rlo = lane & 15, khi = lane >> 4;
    const int srow = t >> 2, sseg = t & 3;                    // xsb stage roles

    if (t < 128) { as_s[t] = 0.f; ad_s[t] = 0.f; }

    f32x4 acc[4][2];
#pragma unroll
    for (int mt = 0; mt < 4; ++mt)
#pragma unroll
        for (int ntl = 0; ntl < 2; ++ntl)
#pragma unroll
            for (int q = 0; q < 4; ++q) acc[mt][ntl][q] = 0.f;

    // prologue: stage head 0's xagg slice
    *(uint4*)&xsb[0][srow * XSB + sseg * 8] =
        *(const uint4*)&xaggb[((size_t)(n0 + srow) * H1 + 0) * 32 + sseg * 8];

    for (int h = 0; h < H1; ++h) {
        const int cur = h & 1;
        __syncthreads();                  // xsb[cur] staged; prev Xs reads done

        // expansion: wave owns c-tile wvu (16 cols of x1 within this head)
        short8v a1 = *(const short8v*)&W1pT[(((size_t)h * 8 + wvu) * 64 + lane) * 8];
        float4 bv4 = *(const float4*)&b1[h * DD + wvu * 16 + khi * 4];
        unsigned short* XsW = (wvu >> 2) ? Xs1 : Xs0;          // write half
        const int gw7 = (wvu * 2 + (khi >> 1)) & 7;            // granule in half
#pragma unroll
        for (int nh = 0; nh < 2; ++nh) {
            f32x4 acc2[4];
#pragma unroll
            for (int j = 0; j < 4; ++j) {
                int nt = nh * 4 + j;
                short8v bfrag = *(const short8v*)&xsb[cur][(nt * 16 + rlo) * XSB + khi * 8];
                f32x4 zz = {0.f, 0.f, 0.f, 0.f};
                acc2[j] = __builtin_amdgcn_mfma_f32_16x16x32_bf16(a1, bfrag, zz, 0, 0, 0);
            }
#pragma unroll
            for (int j = 0; j < 4; ++j) {
                int nt = nh * 4 + j;
                float z0 = acc2[j][0] + bv4.x;
                float z1 = acc2[j][1] + bv4.y;
                float z2 = acc2[j][2] + bv4.z;
                float z3 = acc2[j][3] + bv4.w;
                z0 = z0 > 0.f ? z0 : __expf(z0) - 1.f;
                z1 = z1 > 0.f ? z1 : __expf(z1) - 1.f;
                z2 = z2 > 0.f ? z2 : __expf(z2) - 1.f;
                z3 = z3 > 0.f ? z3 : __expf(z3) - 1.f;
                unsigned int lo = (unsigned int)f2bf(z0) | ((unsigned int)f2bf(z1) << 16);
                unsigned int hi = (unsigned int)f2bf(z2) | ((unsigned int)f2bf(z3) << 16);
                int rown = nt * 16 + rlo;                      // node row
                unsigned offu = rown * 64 + (((gw7 ^ (rown & 7)) << 3) | ((khi & 1) << 2));
                *(uint2*)&XsW[offu] = make_uint2(lo, hi);
            }
        }
        __syncthreads();                  // Xs visible

        // stage next head's xagg slice into the other xsb buffer (overlaps GEMM)
        if (h + 1 < H1) {
            *(uint4*)&xsb[cur ^ 1][srow * XSB + sseg * 8] =
                *(const uint4*)&xaggb[((size_t)(n0 + srow) * H1 + (h + 1)) * 32 + sseg * 8];
        }

        // main GEMM: this head's K=128 (4 sub-K of 32; ks<2 -> Xs0, ks>=2 -> Xs1)
#pragma unroll
        for (int ks = 0; ks < 4; ++ks) {
            const int ktabs = h * 4 + ks;
            const unsigned short* XsR = (ks >> 1) ? Xs1 : Xs0;
            const int g7 = (ks & 1) * 4 + khi;                 // granule in half
            short8v bfr[2];
#pragma unroll
            for (int ntl = 0; ntl < 2; ++ntl) {
                const int nt = cq * 2 + ntl;
                bfr[ntl] = *(const short8v*)&W2p[(((size_t)ktabs * 8 + nt) * 64 + lane) * 8];
            }
#pragma unroll
            for (int mt = 0; mt < 4; ++mt) {
                const int row2 = rh * 64 + mt * 16 + rlo;
                unsigned offu = row2 * 64 + ((g7 ^ (row2 & 7)) << 3);
                short8v af = *(const short8v*)&XsR[offu];
                acc[mt][0] = __builtin_amdgcn_mfma_f32_16x16x32_bf16(af, bfr[0], acc[mt][0], 0, 0, 0);
                acc[mt][1] = __builtin_amdgcn_mfma_f32_16x16x32_bf16(af, bfr[1], acc[mt][1], 0, 0, 0);
            }
        }
    }

    // epilogue: stage acc tile as bf16 into dead Xs buffers, then coalesced copy
    __syncthreads();                      // last head's Xs reads done
#pragma unroll
    for (int mt = 0; mt < 4; ++mt)
#pragma unroll
        for (int ntl = 0; ntl < 2; ++ntl) {
            int col = cq * 32 + ntl * 16 + rlo;
            unsigned short* Xw = (col < 64) ? Xs0 : Xs1;
            int c64 = col & 63;
#pragma unroll
            for (int q = 0; q < 4; ++q) {
                int row = rh * 64 + mt * 16 + khi * 4 + q;
                Xw[row * 64 + c64] = f2bf(acc[mt][ntl][q]);
            }
        }
    __syncthreads();
#pragma unroll
    for (int i = 0; i < 4; ++i) {
        int j = i * 512 + t;              // uint4 index over the 128x128 tile
        int row = j >> 4;                 // 16 uint4 per 128-col row
        int c8 = (j & 15) * 8;
        const unsigned short* S = (c8 < 64) ? Xs0 : Xs1;
        uint4 v = *(const uint4*)&S[row * 64 + (c8 & 63)];
        *(uint4*)&h2b[(size_t)(n0 + row) * DD + c8] = v;
    }

    // fused alpha2 from fp32 accumulators
    float sp[16], dp[16];
#pragma unroll
    for (int mt = 0; mt < 4; ++mt)
#pragma unroll
        for (int q = 0; q < 4; ++q) {
            float a = 0.f, b = 0.f;
#pragma unroll
            for (int ntl = 0; ntl < 2; ++ntl) {
                int col = cq * 32 + ntl * 16 + rlo;
                float v = acc[mt][ntl][q];
                a = fmaf(v, a_src2[col], a);
                b = fmaf(v, a_dst2[col], b);
            }
            sp[mt * 4 + q] = a;
            dp[mt * 4 + q] = b;
        }
#pragma unroll
    for (int off = 1; off < 16; off <<= 1) {
#pragma unroll
        for (int i = 0; i < 16; ++i) {
            sp[i] += __shfl_xor(sp[i], off);
            dp[i] += __shfl_xor(dp[i], off);
        }
    }
    if (rlo == 0) {
#pragma unroll
        for (int mt = 0; mt < 4; ++mt)
#pragma unroll
            for (int q = 0; q < 4; ++q) {
                atomicAdd(&as_s[rh * 64 + mt * 16 + khi * 4 + q], sp[mt * 4 + q]);
                atomicAdd(&ad_s[rh * 64 + mt * 16 + khi * 4 + q], dp[mt * 4 + q]);
            }
    }
    __syncthreads();
    if (t < 128) {
        as2[n0 + t] = as_s[t];
        ad2[n0 + t] = ad_s[t];
    }
}

// ---- layer-2 aggregation (online softmax, bf16 h2) -> x2 --------------------
__global__ void agg2_kernel(const int* __restrict__ rowptr, const int* __restrict__ elist,
                            const unsigned short* __restrict__ h2b,
                            const float* __restrict__ as2, const float* __restrict__ ad2,
                            const float* __restrict__ b2, float* __restrict__ x2) {
    int gid = blockIdx.x * 256 + threadIdx.x;
    int n = gid >> 5, lane = gid & 31;
    if (n >= NN) return;
    int beg = rowptr[n], end = rowptr[n + 1];
    float adn = ad2[n];
    float m = -INFINITY, den = 0.f;
    float4 acc = make_float4(0.f, 0.f, 0.f, 0.f);
    for (int j = beg; j < end; ++j) {
        int s = elist[j];
        float v = lrelu(as2[s] + adn);
        if (v > m) {
            float sc = __expf(m - v);
            den *= sc;
            acc.x *= sc; acc.y *= sc; acc.z *= sc; acc.w *= sc;
            m = v;
        }
        float ex = __expf(v - m);
        den += ex;
        ushort4 hv = *(const ushort4*)&h2b[(size_t)s * DD + lane * 4];
        acc.x = fmaf(ex, bf2f(hv.x), acc.x);
        acc.y = fmaf(ex, bf2f(hv.y), acc.y);
        acc.z = fmaf(ex, bf2f(hv.z), acc.z);
        acc.w = fmaf(ex, bf2f(hv.w), acc.w);
    }
    float inv = 1.f / (den + 1e-16f);
    float4 bv = *(const float4*)&b2[lane * 4];
    float4 r;
    r.x = eluf(acc.x * inv + bv.x);
    r.y = eluf(acc.y * inv + bv.y);
    r.z = eluf(acc.z * inv + bv.z);
    r.w = eluf(acc.w * inv + bv.w);
    *(float4*)&x2[(size_t)n * DD + lane * 4] = r;
}

// ---- fused pooling + FC: block g pools its node range, then out row g -------
__global__ __launch_bounds__(128) void pool_final_kernel(const int* __restrict__ gptr,
                                                         const float* __restrict__ x2,
                                                         const float* __restrict__ Wfc,
                                                         const float* __restrict__ bfc,
                                                         float* __restrict__ out) {
    __shared__ float pl[DD];
    int g = blockIdx.x;
    int c = threadIdx.x;          // 128 channels
    int beg = gptr[g], end = gptr[g + 1];
    float v = -INFINITY;
    for (int n = beg; n < end; ++n)
        v = fmaxf(v, x2[(size_t)n * DD + c]);
    if (beg == end) v = 0.f;      // empty graph -> 0 (isfinite guard)
    pl[c] = v;
    __syncthreads();
    float acc = bfc[c];
#pragma unroll 8
    for (int k = 0; k < DD; ++k)
        acc = fmaf(pl[k], Wfc[k * DD + c], acc);
    out[(size_t)g * DD + c] = acc > 0.f ? acc : 0.f;
}

extern "C" void kernel_launch(void* const* d_in, const int* in_sizes, int n_in,
                              void* d_out, int out_size, void* d_ws, size_t ws_size,
                              hipStream_t stream) {
    const float* x      = (const float*)d_in[0];
    const int*   ei     = (const int*)d_in[1];
    const int*   batch  = (const int*)d_in[3];
    const float* W1     = (const float*)d_in[4];
    const float* a_src1 = (const float*)d_in[5];
    const float* a_dst1 = (const float*)d_in[6];
    const float* b1     = (const float*)d_in[7];
    const float* W2     = (const float*)d_in[8];
    const float* a_src2 = (const float*)d_in[9];
    const float* a_dst2 = (const float*)d_in[10];
    const float* b2     = (const float*)d_in[11];
    const float* Wfc    = (const float*)d_in[12];
    const float* bfc    = (const float*)d_in[13];
    float* out = (float*)d_out;

    // workspace layout — ~105 MB total
    float* wsf    = (float*)d_ws;
    float* as1    = wsf;                                   // NN*H1
    float* ad1    = as1 + (size_t)NN * H1;                 // NN*H1
    float* as2    = ad1 + (size_t)NN * H1;                 // NN
    float* ad2    = as2 + NN;                              // NN
    float* x2     = ad2 + NN;                              // NN*DD
    int*   deg    = (int*)(x2 + (size_t)NN * DD);          // NN
    int*   rowptr = deg + NN;                              // NN+1
    int*   cursor = rowptr + NN + 1;                       // NN
    int*   elist  = cursor + NN;                           // ET
    int*   gptr   = elist + ET;                            // NG+1
    size_t off = (size_t)((char*)(gptr + NG + 1) - (char*)d_ws);
    off = (off + 15) & ~(size_t)15;
    unsigned short* W2p   = (unsigned short*)((char*)d_ws + off);    // KK*DD bf16
    unsigned short* W1pT  = W2p + (size_t)KK * DD;                   // 40960 bf16
    unsigned short* xaggb = W1pT + 40960;                            // NN*H1*32 bf16
    unsigned short* h2b   = xaggb + (size_t)NN * H1 * 32;            // NN*DD bf16

    setup_kernel     <<<1312, 256, 0, stream>>>(W1, W2, a_src1, a_dst1, x, batch,
                                                W2p, W1pT, as1, ad1, deg, gptr);
    count_kernel     <<<(ET + 255) / 256, 256, 0, stream>>>(ei, deg);
    scan_kernel      <<<1, 1024, 0, stream>>>(deg, rowptr, cursor);
    scatter_kernel   <<<(ET + 255) / 256, 256, 0, stream>>>(ei, cursor, elist);
    agg1_kernel      <<<(NN * H1 + 255) / 256, 256, 0, stream>>>(rowptr, elist, x, as1, ad1, xaggb);
    h2_gemm          <<<NN / 128, 512, 0, stream>>>(xaggb, W1pT, b1, W2p, a_src2, a_dst2,
                                                    h2b, as2, ad2);
    agg2_kernel      <<<(NN * 32) / 256, 256, 0, stream>>>(rowptr, elist, h2b, as2, ad2, b2, x2);
    pool_final_kernel<<<NG, 128, 0, stream>>>(gptr, x2, Wfc, bfc, out);
}

// Round 14
// 167.950 us; speedup vs baseline: 1.4508x; 1.2002x over previous
//
#include <hip/hip_runtime.h>
#include <hip/hip_bf16.h>
#include <math.h>

#define NN 65536          // nodes
#define NE 196608         // edges (without self loops)
#define ET (NE + NN)      // edges + self loops = 262144
#define NG 2048           // graphs
#define FIN 9
#define DD 128
#define H1 10
#define KK (H1 * DD)      // 1280
#define LRS 0.2f
#define XSB 36            // xsb row stride (ushorts): 72B rows

typedef __attribute__((ext_vector_type(8))) short short8v;
typedef __attribute__((ext_vector_type(4))) float f32x4;

__device__ __forceinline__ float lrelu(float v) { return v >= 0.f ? v : LRS * v; }
__device__ __forceinline__ float eluf(float v)  { return v > 0.f ? v : expm1f(v); }

// float -> bf16 round-to-nearest-even (3 int ops, no libcall)
__device__ __forceinline__ unsigned short f2bf(float f) {
    unsigned int u = __float_as_uint(f);
    u += 0x7FFFu + ((u >> 16) & 1u);
    return (unsigned short)(u >> 16);
}
__device__ __forceinline__ float bf2f(unsigned short s) {
    return __uint_as_float((unsigned int)s << 16);
}

// ---- setup: packW2 | alpha1+prep | gptr | packW1pT (independent branches) ---
__global__ __launch_bounds__(256) void setup_kernel(
        const float* __restrict__ W1, const float* __restrict__ W2,
        const float* __restrict__ a_src1, const float* __restrict__ a_dst1,
        const float* __restrict__ x, const int* __restrict__ batch,
        unsigned short* __restrict__ W2p, unsigned short* __restrict__ W1pT,
        float* __restrict__ as1, float* __restrict__ ad1,
        int* __restrict__ deg, int* __restrict__ gptr) {
    __shared__ float ws_s[FIN * H1], wd_s[FIN * H1];
    const int b = blockIdx.x;
    const int t = threadIdx.x;
    if (b < 640) {
        // W2 (1280x128 fp32) -> bf16 B-fragment layout
        int idx = b * 256 + t;
        int r  = idx & 7;
        int l  = (idx >> 3) & 63;
        int nt = (idx >> 9) & 7;
        int kt = idx >> 12;
        int k = kt * 32 + ((l >> 4) << 3) + r;
        int n = nt * 16 + (l & 15);
        W2p[idx] = f2bf(W2[(size_t)k * DD + n]);
    } else if (b < 896) {
        if (t < FIN * H1) {
            int f = t / H1, h = t - f * H1;
            float s = 0.f, d = 0.f;
            for (int c = 0; c < DD; ++c) {
                float w = W1[f * KK + h * DD + c];
                s = fmaf(w, a_src1[h * DD + c], s);
                d = fmaf(w, a_dst1[h * DD + c], d);
            }
            ws_s[t] = s;
            wd_s[t] = d;
        }
        __syncthreads();
        int n = (b - 640) * 256 + t;
        float xv[FIN];
#pragma unroll
        for (int f = 0; f < FIN; ++f) xv[f] = x[(size_t)n * FIN + f];
#pragma unroll
        for (int h = 0; h < H1; ++h) {
            float s = 0.f, d = 0.f;
#pragma unroll
            for (int f = 0; f < FIN; ++f) {
                s = fmaf(xv[f], ws_s[f * H1 + h], s);
                d = fmaf(xv[f], wd_s[f * H1 + h], d);
            }
            as1[n * H1 + h] = s;
            ad1[n * H1 + h] = d;
        }
        deg[n] = 0;
    } else if (b < 1152) {
        int n = (b - 896) * 256 + t;
        int bn = batch[n];
        int bp = (n == 0) ? -1 : batch[n - 1];
        for (int g = bp + 1; g <= bn; ++g) gptr[g] = n;
        if (n == NN - 1) {
            for (int g = bn + 1; g <= NG; ++g) gptr[g] = NN;
        }
    } else {
        // W1^T -> bf16 A-fragment layout for the expansion MFMA (K=9 pad 32)
        int idx = (b - 1152) * 256 + t;            // 40960 total
        int r  = idx & 7;
        int l  = (idx >> 3) & 63;
        int mt = (idx >> 9) & 7;
        int h  = idx >> 12;
        int f  = ((l >> 4) << 3) + r;
        int c  = mt * 16 + (l & 15);
        W1pT[idx] = (f < FIN) ? f2bf(W1[(size_t)f * KK + h * DD + c]) : (unsigned short)0;
    }
}

// ---- CSR build: count / coalesced 3-phase scan / scatter --------------------
__global__ void count_kernel(const int* __restrict__ ei, int* __restrict__ deg) {
    int e = blockIdx.x * 256 + threadIdx.x;
    if (e >= ET) return;
    int d = (e < NE) ? ei[NE + e] : e - NE;
    atomicAdd(&deg[d], 1);
}

// phase 1: per-block (256-elem) sums, fully coalesced
__global__ __launch_bounds__(256) void scan1_kernel(const int* __restrict__ deg,
                                                    int* __restrict__ bsum) {
    __shared__ int sc[256];
    int t = threadIdx.x, b = blockIdx.x;
    sc[t] = deg[b * 256 + t];
    __syncthreads();
    for (int off = 128; off > 0; off >>= 1) {
        if (t < off) sc[t] += sc[t + off];
        __syncthreads();
    }
    if (t == 0) bsum[b] = sc[0];
}

// phase 2: exclusive scan of the 256 block sums (single tiny block)
__global__ __launch_bounds__(256) void scan2_kernel(int* __restrict__ bsum,
                                                    int* __restrict__ rowptr) {
    __shared__ int sc[256];
    int t = threadIdx.x;
    int v = bsum[t];
    sc[t] = v;
    __syncthreads();
    for (int off = 1; off < 256; off <<= 1) {
        int u = (t >= off) ? sc[t - off] : 0;
        __syncthreads();
        sc[t] += u;
        __syncthreads();
    }
    bsum[t] = sc[t] - v;               // exclusive prefix
    if (t == 255) rowptr[NN] = sc[255];
}

// phase 3: block-local exclusive scan + offset; coalesced rowptr/cursor writes
__global__ __launch_bounds__(256) void scan3_kernel(const int* __restrict__ deg,
                                                    const int* __restrict__ bsum,
                                                    int* __restrict__ rowptr,
                                                    int* __restrict__ cursor) {
    __shared__ int sc[256];
    int t = threadIdx.x, b = blockIdx.x;
    int i = b * 256 + t;
    int v = deg[i];
    sc[t] = v;
    __syncthreads();
    for (int off = 1; off < 256; off <<= 1) {
        int u = (t >= off) ? sc[t - off] : 0;
        __syncthreads();
        sc[t] += u;
        __syncthreads();
    }
    int r = bsum[b] + sc[t] - v;
    rowptr[i] = r;
    cursor[i] = r;
}

__global__ void scatter_kernel(const int* __restrict__ ei, int* __restrict__ cursor,
                               int* __restrict__ elist) {
    int e = blockIdx.x * 256 + threadIdx.x;
    if (e >= ET) return;
    int s, d;
    if (e < NE) { s = ei[e]; d = ei[NE + e]; } else { s = d = e - NE; }
    int pos = atomicAdd(&cursor[d], 1);
    elist[pos] = s;
}

// ---- layer-1 aggregation: online softmax -> bf16 padded rows ----------------
// xaggb[(n*H1+h)*32 + f] bf16: f 0..8 = xagg/den, f 9..31 = 0 (K=32 MFMA pad).
__global__ void agg1_kernel(const int* __restrict__ rowptr, const int* __restrict__ elist,
                            const float* __restrict__ x,
                            const float* __restrict__ as1, const float* __restrict__ ad1,
                            unsigned short* __restrict__ xaggb) {
    int idx = blockIdx.x * 256 + threadIdx.x;     // NN*H1
    if (idx >= NN * H1) return;
    int d = idx / H1, h = idx - d * H1;
    int beg = rowptr[d], end = rowptr[d + 1];
    float adh = ad1[d * H1 + h];
    float m = -INFINITY, den = 0.f;
    float xa[FIN] = {};
    for (int j = beg; j < end; ++j) {
        int s = elist[j];
        float v = lrelu(as1[s * H1 + h] + adh);
        if (v > m) {
            float sc = __expf(m - v);
            den *= sc;
#pragma unroll
            for (int f = 0; f < FIN; ++f) xa[f] *= sc;
            m = v;
        }
        float ex = __expf(v - m);
        den += ex;
        const float* xs = &x[(size_t)s * FIN];
#pragma unroll
        for (int f = 0; f < FIN; ++f) xa[f] = fmaf(ex, xs[f], xa[f]);
    }
    float inv = 1.f / (den + 1e-16f);
    unsigned int w[16];
#pragma unroll
    for (int i = 0; i < 16; ++i) w[i] = 0u;
#pragma unroll
    for (int f = 0; f < FIN; ++f) {
        unsigned int bv = f2bf(xa[f] * inv);
        w[f >> 1] |= bv << ((f & 1) * 16);
    }
    uint4* dst = (uint4*)&xaggb[(size_t)idx * 32];
    dst[0] = make_uint4(w[0], w[1], w[2], w[3]);
    dst[1] = make_uint4(w[4], w[5], w[6], w[7]);
    dst[2] = make_uint4(w[8], w[9], w[10], w[11]);
    dst[3] = make_uint4(w[12], w[13], w[14], w[15]);
}

// ---- h2 = elu(xagg@W1 + b1) @ W2, BOTH matmuls on MFMA + alpha2 epilogue ----
__global__ __launch_bounds__(512, 4) void h2_gemm(
        const unsigned short* __restrict__ xaggb,
        const unsigned short* __restrict__ W1pT,
        const float* __restrict__ b1,
        const unsigned short* __restrict__ W2p,
        const float* __restrict__ a_src2, const float* __restrict__ a_dst2,
        unsigned short* __restrict__ h2b, float* __restrict__ as2,
        float* __restrict__ ad2) {
    __shared__ unsigned short Xs0[128 * 64];          // 16 KB, v6 swizzle
    __shared__ unsigned short Xs1[128 * 64];          // 16 KB
    __shared__ unsigned short xsb[2][128 * XSB];      // 2 x 9 KB
    __shared__ float as_s[128], ad_s[128];
    const int t = threadIdx.x;
    const int n0 = blockIdx.x * 128;
    const int lane = t & 63;
    const int wvu = __builtin_amdgcn_readfirstlane(t >> 6);   // 0..7
    const int rh = wvu & 1, cq = wvu >> 1;                    // main-GEMM roles
    const int rlo = lane & 15, khi = lane >> 4;
    const int srow = t >> 2, sseg = t & 3;                    // xsb stage roles

    if (t < 128) { as_s[t] = 0.f; ad_s[t] = 0.f; }

    f32x4 acc[4][2];
#pragma unroll
    for (int mt = 0; mt < 4; ++mt)
#pragma unroll
        for (int ntl = 0; ntl < 2; ++ntl)
#pragma unroll
            for (int q = 0; q < 4; ++q) acc[mt][ntl][q] = 0.f;

    // prologue: stage head 0's xagg slice
    *(uint4*)&xsb[0][srow * XSB + sseg * 8] =
        *(const uint4*)&xaggb[((size_t)(n0 + srow) * H1 + 0) * 32 + sseg * 8];

    for (int h = 0; h < H1; ++h) {
        const int cur = h & 1;
        __syncthreads();                  // xsb[cur] staged; prev Xs reads done

        // expansion: wave owns c-tile wvu (16 cols of x1 within this head)
        short8v a1 = *(const short8v*)&W1pT[(((size_t)h * 8 + wvu) * 64 + lane) * 8];
        float4 bv4 = *(const float4*)&b1[h * DD + wvu * 16 + khi * 4];
        unsigned short* XsW = (wvu >> 2) ? Xs1 : Xs0;          // write half
        const int gw7 = (wvu * 2 + (khi >> 1)) & 7;            // granule in half
#pragma unroll
        for (int nh = 0; nh < 2; ++nh) {
            f32x4 acc2[4];
#pragma unroll
            for (int j = 0; j < 4; ++j) {
                int nt = nh * 4 + j;
                short8v bfrag = *(const short8v*)&xsb[cur][(nt * 16 + rlo) * XSB + khi * 8];
                f32x4 zz = {0.f, 0.f, 0.f, 0.f};
                acc2[j] = __builtin_amdgcn_mfma_f32_16x16x32_bf16(a1, bfrag, zz, 0, 0, 0);
            }
#pragma unroll
            for (int j = 0; j < 4; ++j) {
                int nt = nh * 4 + j;
                float z0 = acc2[j][0] + bv4.x;
                float z1 = acc2[j][1] + bv4.y;
                float z2 = acc2[j][2] + bv4.z;
                float z3 = acc2[j][3] + bv4.w;
                z0 = z0 > 0.f ? z0 : __expf(z0) - 1.f;
                z1 = z1 > 0.f ? z1 : __expf(z1) - 1.f;
                z2 = z2 > 0.f ? z2 : __expf(z2) - 1.f;
                z3 = z3 > 0.f ? z3 : __expf(z3) - 1.f;
                unsigned int lo = (unsigned int)f2bf(z0) | ((unsigned int)f2bf(z1) << 16);
                unsigned int hi = (unsigned int)f2bf(z2) | ((unsigned int)f2bf(z3) << 16);
                int rown = nt * 16 + rlo;                      // node row
                unsigned offu = rown * 64 + (((gw7 ^ (rown & 7)) << 3) | ((khi & 1) << 2));
                *(uint2*)&XsW[offu] = make_uint2(lo, hi);
            }
        }
        __syncthreads();                  // Xs visible

        // stage next head's xagg slice into the other xsb buffer (overlaps GEMM)
        if (h + 1 < H1) {
            *(uint4*)&xsb[cur ^ 1][srow * XSB + sseg * 8] =
                *(const uint4*)&xaggb[((size_t)(n0 + srow) * H1 + (h + 1)) * 32 + sseg * 8];
        }

        // main GEMM: this head's K=128 (4 sub-K of 32; ks<2 -> Xs0, ks>=2 -> Xs1)
#pragma unroll
        for (int ks = 0; ks < 4; ++ks) {
            const int ktabs = h * 4 + ks;
            const unsigned short* XsR = (ks >> 1) ? Xs1 : Xs0;
            const int g7 = (ks & 1) * 4 + khi;                 // granule in half
            short8v bfr[2];
#pragma unroll
            for (int ntl = 0; ntl < 2; ++ntl) {
                const int nt = cq * 2 + ntl;
                bfr[ntl] = *(const short8v*)&W2p[(((size_t)ktabs * 8 + nt) * 64 + lane) * 8];
            }
#pragma unroll
            for (int mt = 0; mt < 4; ++mt) {
                const int row2 = rh * 64 + mt * 16 + rlo;
                unsigned offu = row2 * 64 + ((g7 ^ (row2 & 7)) << 3);
                short8v af = *(const short8v*)&XsR[offu];
                acc[mt][0] = __builtin_amdgcn_mfma_f32_16x16x32_bf16(af, bfr[0], acc[mt][0], 0, 0, 0);
                acc[mt][1] = __builtin_amdgcn_mfma_f32_16x16x32_bf16(af, bfr[1], acc[mt][1], 0, 0, 0);
            }
        }
    }

    // epilogue: stage acc tile as bf16 into dead Xs buffers, then coalesced copy
    __syncthreads();                      // last head's Xs reads done
#pragma unroll
    for (int mt = 0; mt < 4; ++mt)
#pragma unroll
        for (int ntl = 0; ntl < 2; ++ntl) {
            int col = cq * 32 + ntl * 16 + rlo;
            unsigned short* Xw = (col < 64) ? Xs0 : Xs1;
            int c64 = col & 63;
#pragma unroll
            for (int q = 0; q < 4; ++q) {
                int row = rh * 64 + mt * 16 + khi * 4 + q;
                Xw[row * 64 + c64] = f2bf(acc[mt][ntl][q]);
            }
        }
    __syncthreads();
#pragma unroll
    for (int i = 0; i < 4; ++i) {
        int j = i * 512 + t;              // uint4 index over the 128x128 tile
        int row = j >> 4;                 // 16 uint4 per 128-col row
        int c8 = (j & 15) * 8;
        const unsigned short* S = (c8 < 64) ? Xs0 : Xs1;
        uint4 v = *(const uint4*)&S[row * 64 + (c8 & 63)];
        *(uint4*)&h2b[(size_t)(n0 + row) * DD + c8] = v;
    }

    // fused alpha2 from fp32 accumulators
    float sp[16], dp[16];
#pragma unroll
    for (int mt = 0; mt < 4; ++mt)
#pragma unroll
        for (int q = 0; q < 4; ++q) {
            float a = 0.f, b = 0.f;
#pragma unroll
            for (int ntl = 0; ntl < 2; ++ntl) {
                int col = cq * 32 + ntl * 16 + rlo;
                float v = acc[mt][ntl][q];
                a = fmaf(v, a_src2[col], a);
                b = fmaf(v, a_dst2[col], b);
            }
            sp[mt * 4 + q] = a;
            dp[mt * 4 + q] = b;
        }
#pragma unroll
    for (int off = 1; off < 16; off <<= 1) {
#pragma unroll
        for (int i = 0; i < 16; ++i) {
            sp[i] += __shfl_xor(sp[i], off);
            dp[i] += __shfl_xor(dp[i], off);
        }
    }
    if (rlo == 0) {
#pragma unroll
        for (int mt = 0; mt < 4; ++mt)
#pragma unroll
            for (int q = 0; q < 4; ++q) {
                atomicAdd(&as_s[rh * 64 + mt * 16 + khi * 4 + q], sp[mt * 4 + q]);
                atomicAdd(&ad_s[rh * 64 + mt * 16 + khi * 4 + q], dp[mt * 4 + q]);
            }
    }
    __syncthreads();
    if (t < 128) {
        as2[n0 + t] = as_s[t];
        ad2[n0 + t] = ad_s[t];
    }
}

// ---- layer-2 aggregation (online softmax, bf16 h2) -> x2 (bf16) -------------
__global__ void agg2_kernel(const int* __restrict__ rowptr, const int* __restrict__ elist,
                            const unsigned short* __restrict__ h2b,
                            const float* __restrict__ as2, const float* __restrict__ ad2,
                            const float* __restrict__ b2, unsigned short* __restrict__ x2b) {
    int gid = blockIdx.x * 256 + threadIdx.x;
    int n = gid >> 5, lane = gid & 31;
    if (n >= NN) return;
    int beg = rowptr[n], end = rowptr[n + 1];
    float adn = ad2[n];
    float m = -INFINITY, den = 0.f;
    float4 acc = make_float4(0.f, 0.f, 0.f, 0.f);
    for (int j = beg; j < end; ++j) {
        int s = elist[j];
        float v = lrelu(as2[s] + adn);
        if (v > m) {
            float sc = __expf(m - v);
            den *= sc;
            acc.x *= sc; acc.y *= sc; acc.z *= sc; acc.w *= sc;
            m = v;
        }
        float ex = __expf(v - m);
        den += ex;
        ushort4 hv = *(const ushort4*)&h2b[(size_t)s * DD + lane * 4];
        acc.x = fmaf(ex, bf2f(hv.x), acc.x);
        acc.y = fmaf(ex, bf2f(hv.y), acc.y);
        acc.z = fmaf(ex, bf2f(hv.z), acc.z);
        acc.w = fmaf(ex, bf2f(hv.w), acc.w);
    }
    float inv = 1.f / (den + 1e-16f);
    float4 bv = *(const float4*)&b2[lane * 4];
    ushort4 o;
    o.x = f2bf(eluf(acc.x * inv + bv.x));
    o.y = f2bf(eluf(acc.y * inv + bv.y));
    o.z = f2bf(eluf(acc.z * inv + bv.z));
    o.w = f2bf(eluf(acc.w * inv + bv.w));
    *(ushort4*)&x2b[(size_t)n * DD + lane * 4] = o;
}

// ---- fused pooling + FC: block g pools its node range, then out row g -------
__global__ __launch_bounds__(128) void pool_final_kernel(const int* __restrict__ gptr,
                                                         const unsigned short* __restrict__ x2b,
                                                         const float* __restrict__ Wfc,
                                                         const float* __restrict__ bfc,
                                                         float* __restrict__ out) {
    __shared__ float pl[DD];
    int g = blockIdx.x;
    int c = threadIdx.x;          // 128 channels
    int beg = gptr[g], end = gptr[g + 1];
    float v = -INFINITY;
    for (int n = beg; n < end; ++n)
        v = fmaxf(v, bf2f(x2b[(size_t)n * DD + c]));
    if (beg == end) v = 0.f;      // empty graph -> 0 (isfinite guard)
    pl[c] = v;
    __syncthreads();
    float acc = bfc[c];
#pragma unroll 8
    for (int k = 0; k < DD; ++k)
        acc = fmaf(pl[k], Wfc[k * DD + c], acc);
    out[(size_t)g * DD + c] = acc > 0.f ? acc : 0.f;
}

extern "C" void kernel_launch(void* const* d_in, const int* in_sizes, int n_in,
                              void* d_out, int out_size, void* d_ws, size_t ws_size,
                              hipStream_t stream) {
    const float* x      = (const float*)d_in[0];
    const int*   ei     = (const int*)d_in[1];
    const int*   batch  = (const int*)d_in[3];
    const float* W1     = (const float*)d_in[4];
    const float* a_src1 = (const float*)d_in[5];
    const float* a_dst1 = (const float*)d_in[6];
    const float* b1     = (const float*)d_in[7];
    const float* W2     = (const float*)d_in[8];
    const float* a_src2 = (const float*)d_in[9];
    const float* a_dst2 = (const float*)d_in[10];
    const float* b2     = (const float*)d_in[11];
    const float* Wfc    = (const float*)d_in[12];
    const float* bfc    = (const float*)d_in[13];
    float* out = (float*)d_out;

    // workspace layout — ~90 MB total
    float* wsf    = (float*)d_ws;
    float* as1    = wsf;                                   // NN*H1
    float* ad1    = as1 + (size_t)NN * H1;                 // NN*H1
    float* as2    = ad1 + (size_t)NN * H1;                 // NN
    float* ad2    = as2 + NN;                              // NN
    int*   deg    = (int*)(ad2 + NN);                      // NN
    int*   rowptr = deg + NN;                              // NN+1
    int*   cursor = rowptr + NN + 1;                       // NN
    int*   elist  = cursor + NN;                           // ET
    int*   gptr   = elist + ET;                            // NG+1
    int*   bsum   = gptr + NG + 1;                         // 256
    size_t off = (size_t)((char*)(bsum + 256) - (char*)d_ws);
    off = (off + 15) & ~(size_t)15;
    unsigned short* W2p   = (unsigned short*)((char*)d_ws + off);    // KK*DD bf16
    unsigned short* W1pT  = W2p + (size_t)KK * DD;                   // 40960 bf16
    unsigned short* xaggb = W1pT + 40960;                            // NN*H1*32 bf16
    unsigned short* h2b   = xaggb + (size_t)NN * H1 * 32;            // NN*DD bf16
    unsigned short* x2b   = h2b + (size_t)NN * DD;                   // NN*DD bf16

    setup_kernel     <<<1312, 256, 0, stream>>>(W1, W2, a_src1, a_dst1, x, batch,
                                                W2p, W1pT, as1, ad1, deg, gptr);
    count_kernel     <<<(ET + 255) / 256, 256, 0, stream>>>(ei, deg);
    scan1_kernel     <<<256, 256, 0, stream>>>(deg, bsum);
    scan2_kernel     <<<1, 256, 0, stream>>>(bsum, rowptr);
    scan3_kernel     <<<256, 256, 0, stream>>>(deg, bsum, rowptr, cursor);
    scatter_kernel   <<<(ET + 255) / 256, 256, 0, stream>>>(ei, cursor, elist);
    agg1_kernel      <<<(NN * H1 + 255) / 256, 256, 0, stream>>>(rowptr, elist, x, as1, ad1, xaggb);
    h2_gemm          <<<NN / 128, 512, 0, stream>>>(xaggb, W1pT, b1, W2p, a_src2, a_dst2,
                                                    h2b, as2, ad2);
    agg2_kernel      <<<(NN * 32) / 256, 256, 0, stream>>>(rowptr, elist, h2b, as2, ad2, b2, x2b);
    pool_final_kernel<<<NG, 128, 0, stream>>>(gptr, x2b, Wfc, bfc, out);
}